// Round 7
// baseline (703.111 us; speedup 1.0000x reference)
//
#include <hip/hip_runtime.h>
#include <cstdint>
#include <type_traits>

// GNN GATv2 x3 + mean-pool + MLP.
// All GEMMs on fp16 MFMA; fp16 tables; fp16 CSR edge features (self-loop =
// last CSR entry). R17 == R16 resubmit (container infra failure, no kernel
// defect found on audit): (1) fused L/R node-transform GEMMs -- one kernel
// reads the A-fragments ONCE and runs both weight matrices (was gridDim.y=2
// re-reading A per half; 57MB/iter wasted). (2) layer-3 edge kernel ported
// to the k2w structure: one node/wave, 4 edges/iter across 16-lane groups,
// wave-uniform control flow, DPP row reduce (k2w1). CSR build = R15
// (rank_hist + atomic-free place). k2w unchanged (R12 champion).
constexpr int GNUM = 128;   // graphs

typedef _Float16 h2 __attribute__((ext_vector_type(2)));
typedef _Float16 h4 __attribute__((ext_vector_type(4)));
typedef _Float16 h8 __attribute__((ext_vector_type(8)));
typedef float f4 __attribute__((ext_vector_type(4)));

// v += dpp_shuffle<CTRL>(v) -- pure-VALU cross-lane add (no DS pipe).
// 0xB1 quad_perm[1,0,3,2] (xor1), 0x4E quad_perm[2,3,0,1] (xor2),
// 0x141 row_half_mirror (xor4-equiv once quads uniform),
// 0x140 row_mirror (xor8-equiv once octs uniform). DPP rows = 16 lanes.
template <int CTRL>
__device__ __forceinline__ float dppadd(float v) {
  union U { float f; int i; };
  U u, r;
  u.f = v;
  r.i = __builtin_amdgcn_update_dpp(0, u.i, CTRL, 0xF, 0xF, true);
  return v + r.f;
}

__device__ __forceinline__ float hdot2(h2 a, h2 b, float c) {
#if __has_builtin(__builtin_amdgcn_fdot2)
  return __builtin_amdgcn_fdot2(a, b, c, false);
#else
  return c + (float)a[0] * (float)b[0] + (float)a[1] * (float)b[1];
#endif
}

// ---------------------------------------------------------------- setup kernels

// R15: histogram + rank in one atomic pass. The atomic's return value is
// this edge's rank among edges sharing its dst (order arbitrary but unique).
__global__ __launch_bounds__(256) void rank_hist_kernel(const int* __restrict__ dst,
                                                        int* __restrict__ cnt,
                                                        int* __restrict__ rank, int E) {
  int i = blockIdx.x * 256 + threadIdx.x;
  if (i >= E) return;
  rank[i] = atomicAdd(&cnt[dst[i]], 1);
}

// ---- 3-phase parallel exclusive scan of (cnt[i]+1), 512 elems per block ----
__global__ __launch_bounds__(256) void scan_part_kernel(const int* __restrict__ cnt,
                                                        int* __restrict__ bpart, int n) {
  __shared__ int red[256];
  int base = blockIdx.x * 512;
  int t = threadIdx.x;
  int s = 0;
  int i0 = base + t, i1 = base + 256 + t;
  if (i0 < n) s += cnt[i0] + 1;
  if (i1 < n) s += cnt[i1] + 1;
  red[t] = s;
  __syncthreads();
  for (int off = 128; off > 0; off >>= 1) {
    if (t < off) red[t] += red[t + off];
    __syncthreads();
  }
  if (t == 0) bpart[blockIdx.x] = red[0];
}

// scan of block partials + (fused) graph-boundary binary search
__global__ __launch_bounds__(1024) void scan_top_kernel(const int* __restrict__ bpart,
                                                        int* __restrict__ boff,
                                                        int* __restrict__ row_ptr,
                                                        const int* __restrict__ batch,
                                                        int* __restrict__ gstart,
                                                        int B, int n) {
  __shared__ int buf[1024];
  int t = threadIdx.x;
  buf[t] = (t < B) ? bpart[t] : 0;
  __syncthreads();
  for (int off = 1; off < 1024; off <<= 1) {
    int v = (t >= off) ? buf[t - off] : 0;
    __syncthreads();
    buf[t] += v;
    __syncthreads();
  }
  if (t < B) boff[t] = (t == 0) ? 0 : buf[t - 1];
  if (t == 0) row_ptr[n] = buf[1023];
  // fused gbound: graph g's node range start (batch is sorted)
  if (t <= GNUM) {
    int lo = 0, hi = n;
    while (lo < hi) {
      int mid = (lo + hi) >> 1;
      if (batch[mid] < t) lo = mid + 1; else hi = mid;
    }
    gstart[t] = lo;
  }
}

// writes row_ptr (exclusive prefix of cnt[i]+1)
__global__ __launch_bounds__(256) void scan_write_kernel(const int* __restrict__ cnt,
                                                         const int* __restrict__ boff,
                                                         int* __restrict__ row_ptr, int n) {
  __shared__ int red[256];
  int base = blockIdx.x * 512;
  int t = threadIdx.x;
  int i0 = base + 2 * t, i1 = base + 2 * t + 1;
  int v0 = (i0 < n) ? cnt[i0] + 1 : 0;
  int v1 = (i1 < n) ? cnt[i1] + 1 : 0;
  int val = v0 + v1;
  red[t] = val;
  __syncthreads();
  for (int off = 1; off < 256; off <<= 1) {
    int u = (t >= off) ? red[t - off] : 0;
    __syncthreads();
    red[t] += u;
    __syncthreads();
  }
  int o = boff[blockIdx.x] + red[t] - val;   // exclusive prefix for this pair
  if (i0 < n) row_ptr[i0] = o;
  if (i1 < n) row_ptr[i1] = o + v0;
}

// R15: ATOMIC-FREE placement. slot = row_ptr[dst] + rank (unique, < self
// slot). Sequential reads, fire-and-forget random stores.
__global__ __launch_bounds__(256) void place_kernel(const int* __restrict__ src,
                                                    const int* __restrict__ dst,
                                                    const int* __restrict__ rank,
                                                    const int* __restrict__ row_ptr,
                                                    const float* __restrict__ ea,
                                                    int* __restrict__ csr_src,
                                                    _Float16* __restrict__ ea_csr, int E) {
  int i = blockIdx.x * 256 + threadIdx.x;
  if (i >= E) return;
  int d = dst[i];
  int p = row_ptr[d] + rank[i];
  csr_src[p] = src[i];
  float4 e0 = *(const float4*)&ea[(size_t)i * 8];
  float4 e1 = *(const float4*)&ea[(size_t)i * 8 + 4];
  h8 v;
  v[0] = (_Float16)e0.x; v[1] = (_Float16)e0.y; v[2] = (_Float16)e0.z; v[3] = (_Float16)e0.w;
  v[4] = (_Float16)e1.x; v[5] = (_Float16)e1.y; v[6] = (_Float16)e1.z; v[7] = (_Float16)e1.w;
  *(h8*)&ea_csr[(size_t)p * 8] = v;
}

// fill self-loop slot (last of each segment) with segment-mean attrs.
// 8 threads per node (one per edge channel).
__global__ __launch_bounds__(256) void selfloop_kernel(const int* __restrict__ row_ptr,
                                                       int* __restrict__ csr_src,
                                                       _Float16* __restrict__ ea_csr, int n) {
  int idx = blockIdx.x * 256 + threadIdx.x;
  int i = idx >> 3, c = idx & 7;
  if (i >= n) return;
  int s = row_ptr[i], e = row_ptr[i + 1] - 1;   // [s,e) real edges, e = self slot
  float a = 0.f;
  for (int j = s; j < e; j++) a += (float)ea_csr[(size_t)j * 8 + c];
  float inv = 1.f / fmaxf((float)(e - s), 1.f);
  ea_csr[(size_t)e * 8 + c] = (_Float16)(a * inv);
  if (c == 0) csr_src[e] = i;
}

// pack all 6 weight matrices f32 -> fp16 MFMA B-fragment order in one launch.
// blockIdx.y selects matrix; zero-pad K to Kpad.
__global__ __launch_bounds__(256) void pack_all_kernel(
    const float* __restrict__ wl1, _Float16* __restrict__ p1l,
    const float* __restrict__ wr1, _Float16* __restrict__ p1r,
    const float* __restrict__ wl2, _Float16* __restrict__ p2l,
    const float* __restrict__ wr2, _Float16* __restrict__ p2r,
    const float* __restrict__ wl3, _Float16* __restrict__ p3l,
    const float* __restrict__ wr3, _Float16* __restrict__ p3r) {
  int y = blockIdx.y;
  const float* w; _Float16* wp; int Kreal, Kpad, NC;
  switch (y) {
    case 0: w = wl1; wp = p1l; Kreal = 16;  Kpad = 32;  NC = 128; break;
    case 1: w = wr1; wp = p1r; Kreal = 16;  Kpad = 32;  NC = 128; break;
    case 2: w = wl2; wp = p2l; Kreal = 128; Kpad = 128; NC = 128; break;
    case 3: w = wr2; wp = p2r; Kreal = 128; Kpad = 128; NC = 128; break;
    case 4: w = wl3; wp = p3l; Kreal = 128; Kpad = 128; NC = 32;  break;
    default: w = wr3; wp = p3r; Kreal = 128; Kpad = 128; NC = 32; break;
  }
  int KB = Kpad / 32;
  int total = (NC / 16) * KB * 64;
  int idx = blockIdx.x * 256 + threadIdx.x;
  if (idx >= total) return;
  int lane = idx & 63;
  int blk = idx >> 6;
  int nt = blk / KB, kb = blk % KB;
  int col = nt * 16 + (lane & 15);
  int krow = kb * 32 + (lane >> 4) * 8;
  h8 v;
#pragma unroll
  for (int j = 0; j < 8; j++)
    v[j] = (krow + j < Kreal) ? (_Float16)w[(size_t)(krow + j) * NC + col] : (_Float16)0.f;
  *(h8*)&wp[(size_t)idx * 8] = v;
}

// ---------------------------------------------------------------- node transform GEMMs

// R16: FUSED L+R fp16 MFMA, K=128. A-fragments loaded once, both weight
// matrices applied. 256 thr = 4 waves, 16 nodes/wave, 64 nodes/block.
template <int K, int NCOLS>
__global__ __launch_bounds__(256) void k1mf_kernel(const _Float16* __restrict__ x,
                                                   const _Float16* __restrict__ wpL,
                                                   const float* __restrict__ bL,
                                                   _Float16* __restrict__ outL,
                                                   const _Float16* __restrict__ wpR,
                                                   const float* __restrict__ bR,
                                                   _Float16* __restrict__ outR, int n) {
  constexpr int NT = NCOLS / 16, KB = K / 32;

  int tid = threadIdx.x;
  int wave = tid >> 6, lane = tid & 63;
  int m = lane & 15, quad = lane >> 4;
  int node0 = blockIdx.x * 64 + wave * 16;

  h8 afrag[KB];
  int anode = node0 + m;
  if (anode < n) {
#pragma unroll
    for (int kb = 0; kb < KB; kb++)
      afrag[kb] = *(const h8*)&x[(size_t)anode * K + kb * 32 + quad * 8];
  } else {
#pragma unroll
    for (int kb = 0; kb < KB; kb++) afrag[kb] = (h8)(_Float16)0.f;
  }

  f4 accL[NT] = {}, accR[NT] = {};
#pragma unroll
  for (int nt = 0; nt < NT; nt++) {
#pragma unroll
    for (int kb = 0; kb < KB; kb++) {
      h8 bfL = *(const h8*)&wpL[((size_t)(nt * KB + kb) * 64 + lane) * 8];
      accL[nt] = __builtin_amdgcn_mfma_f32_16x16x32_f16(afrag[kb], bfL, accL[nt], 0, 0, 0);
      h8 bfR = *(const h8*)&wpR[((size_t)(nt * KB + kb) * 64 + lane) * 8];
      accR[nt] = __builtin_amdgcn_mfma_f32_16x16x32_f16(afrag[kb], bfR, accR[nt], 0, 0, 0);
    }
  }

#pragma unroll
  for (int nt = 0; nt < NT; nt++) {
#pragma unroll
    for (int r = 0; r < 4; r++) {
      int row = node0 + quad * 4 + r;
      if (row < n) {
        int col = nt * 16 + m;
        outL[(size_t)row * NCOLS + col] = (_Float16)(accL[nt][r] + bL[col]);
        outR[(size_t)row * NCOLS + col] = (_Float16)(accR[nt][r] + bR[col]);
      }
    }
  }
}

// R16: FUSED L+R, Kreal=16 zero-padded to 32 (layer 1); reads f32 x directly
// and converts in-register.
template <int NCOLS>
__global__ __launch_bounds__(256) void k1m16f_kernel(const float* __restrict__ x,
                                                     const _Float16* __restrict__ wpL,
                                                     const float* __restrict__ bL,
                                                     _Float16* __restrict__ outL,
                                                     const _Float16* __restrict__ wpR,
                                                     const float* __restrict__ bR,
                                                     _Float16* __restrict__ outR, int n) {
  constexpr int NT = NCOLS / 16;

  int tid = threadIdx.x;
  int wave = tid >> 6, lane = tid & 63;
  int m = lane & 15, quad = lane >> 4;
  int node0 = blockIdx.x * 64 + wave * 16;

  int anode = node0 + m;
  h8 afrag = (h8)(_Float16)0.f;
  if (anode < n && quad < 2) {
    float4 v0 = *(const float4*)&x[(size_t)anode * 16 + quad * 8];
    float4 v1 = *(const float4*)&x[(size_t)anode * 16 + quad * 8 + 4];
    afrag[0] = (_Float16)v0.x; afrag[1] = (_Float16)v0.y;
    afrag[2] = (_Float16)v0.z; afrag[3] = (_Float16)v0.w;
    afrag[4] = (_Float16)v1.x; afrag[5] = (_Float16)v1.y;
    afrag[6] = (_Float16)v1.z; afrag[7] = (_Float16)v1.w;
  }

  f4 accL[NT] = {}, accR[NT] = {};
#pragma unroll
  for (int nt = 0; nt < NT; nt++) {
    h8 bfL = *(const h8*)&wpL[((size_t)nt * 64 + lane) * 8];
    accL[nt] = __builtin_amdgcn_mfma_f32_16x16x32_f16(afrag, bfL, accL[nt], 0, 0, 0);
    h8 bfR = *(const h8*)&wpR[((size_t)nt * 64 + lane) * 8];
    accR[nt] = __builtin_amdgcn_mfma_f32_16x16x32_f16(afrag, bfR, accR[nt], 0, 0, 0);
  }

#pragma unroll
  for (int nt = 0; nt < NT; nt++) {
#pragma unroll
    for (int r = 0; r < 4; r++) {
      int row = node0 + quad * 4 + r;
      if (row < n) {
        int col = nt * 16 + m;
        outL[(size_t)row * NCOLS + col] = (_Float16)(accL[nt][r] + bL[col]);
        outR[(size_t)row * NCOLS + col] = (_Float16)(accR[nt][r] + bR[col]);
      }
    }
  }
}

// ---------------------------------------------------------------- fused GATv2 edge+softmax+aggregate
// R12 (H=4): one node per wave, 64 lanes x 2 channels. Edge metadata on the
// scalar pipe. 3-stage software pipeline per iteration:
//   A: idx+ea s_loads for pair p+2   (breaks s_load->gather serialization)
//   B: xl gathers for pair p+1       (indices resident since last iter)
//   C: compute pair p                (DPP reduce, fdot2, masked tail)
// One-pass softmax (no max-shift; logits O(1)); att pre-scaled by log2(e).
__global__ __launch_bounds__(256) void k2w_kernel(
    const _Float16* __restrict__ xl, const _Float16* __restrict__ xr,
    const int* __restrict__ row_ptr, const int* __restrict__ csr_src,
    const _Float16* __restrict__ ea_csr, const float* __restrict__ we,
    const float* __restrict__ att, const float* __restrict__ bc,
    _Float16* __restrict__ out, int n) {
  int tid = threadIdx.x;
  int lane = tid & 63;
  int node = blockIdx.x * 4 + (tid >> 6);
  if (node >= n) return;
  int c0 = lane << 1;          // 2 channels per lane; head = lane>>4

  int start = __builtin_amdgcn_readfirstlane(row_ptr[node]);
  int end   = __builtin_amdgcn_readfirstlane(row_ptr[node + 1]);   // len >= 1 (self loop)
  int len = end - start;
  int pairs = (len + 1) >> 1;

  // ---- pipeline prologue: pair0 idx+ea first (longest latency) ----
  int j1 = (start + 1 < end) ? start + 1 : start;
  float m1 = (start + 1 < end) ? 1.f : 0.f;
  int s0 = __builtin_amdgcn_readfirstlane(csr_src[start]);
  int s1 = __builtin_amdgcn_readfirstlane(csr_src[j1]);
  h8 e0 = *(const h8*)&ea_csr[(size_t)start * 8];
  h8 e1 = *(const h8*)&ea_csr[(size_t)j1 * 8];

  // per-lane tables (independent work to overlap the s_loads above)
  h2 w2[8];
#pragma unroll
  for (int k = 0; k < 8; k++) {
    float2 v = *(const float2*)&we[k * 128 + c0];
    w2[k] = h2{(_Float16)v.x, (_Float16)v.y};
  }
  const float LOG2E = 1.44269504088896f;
  float2 av = *(const float2*)&att[c0];
  h2 a2 = h2{(_Float16)(av.x * LOG2E), (_Float16)(av.y * LOG2E)};
  h2 xr2 = *(const h2*)&xr[(size_t)node * 128 + c0];
  const h2 p2 = h2{(_Float16)0.2f, (_Float16)0.2f};

  // pair0 gathers
  h2 x0 = *(const h2*)&xl[(uint32_t)s0 * 128u + (uint32_t)c0];
  h2 x1 = *(const h2*)&xl[(uint32_t)s1 * 128u + (uint32_t)c0];

  // pair1 idx+ea
  int jn = start + 2;
  int k0 = (jn < end) ? jn : start;
  int k1 = (jn + 1 < end) ? jn + 1 : k0;
  float m1n = (jn + 1 < end) ? 1.f : 0.f;
  int s0n = __builtin_amdgcn_readfirstlane(csr_src[k0]);
  int s1n = __builtin_amdgcn_readfirstlane(csr_src[k1]);
  h8 e0n = *(const h8*)&ea_csr[(size_t)k0 * 8];
  h8 e1n = *(const h8*)&ea_csr[(size_t)k1 * 8];

  float s = 0.f, acc0 = 0.f, acc1 = 0.f;

#pragma unroll 2
  for (int p = 0; p < pairs; p++) {
    // ---- stage A: idx+ea for pair p+2 (scalar pipe, SALU clamps) ----
    int ja = start + 2 * (p + 2);
    int ka0 = (ja < end) ? ja : start;
    int ka1 = (ja + 1 < end) ? ja + 1 : ka0;
    float m1a = (ja + 1 < end) ? 1.f : 0.f;
    int s0a = __builtin_amdgcn_readfirstlane(csr_src[ka0]);
    int s1a = __builtin_amdgcn_readfirstlane(csr_src[ka1]);
    h8 e0a = *(const h8*)&ea_csr[(size_t)ka0 * 8];
    h8 e1a = *(const h8*)&ea_csr[(size_t)ka1 * 8];

    // ---- stage B: xl gathers for pair p+1 (indices already resident) ----
    h2 x0n = *(const h2*)&xl[(uint32_t)s0n * 128u + (uint32_t)c0];
    h2 x1n = *(const h2*)&xl[(uint32_t)s1n * 128u + (uint32_t)c0];

    // ---- stage C: compute pair p ----
    h2 t0 = x0 + xr2;
    h2 t1 = x1 + xr2;
#pragma unroll
    for (int k = 0; k < 8; k++) {
      t0 += h2{e0[k], e0[k]} * w2[k];
      t1 += h2{e1[k], e1[k]} * w2[k];
    }
    t0 = __builtin_elementwise_max(t0, t0 * p2);
    t1 = __builtin_elementwise_max(t1, t1 * p2);
    float part0 = hdot2(t0, a2, 0.f);
    float part1 = hdot2(t1, a2, 0.f);
    // 16-lane head reduce, pure VALU (DPP)
    part0 = dppadd<0xB1>(part0);   part1 = dppadd<0xB1>(part1);
    part0 = dppadd<0x4E>(part0);   part1 = dppadd<0x4E>(part1);
    part0 = dppadd<0x141>(part0);  part1 = dppadd<0x141>(part1);
    part0 = dppadd<0x140>(part0);  part1 = dppadd<0x140>(part1);
    float pe0 = __builtin_amdgcn_exp2f(part0);
    float pe1 = __builtin_amdgcn_exp2f(part1) * m1;   // mask dummy edge
    s += pe0 + pe1;
    acc0 += pe0 * (float)x0[0] + pe1 * (float)x1[0];
    acc1 += pe0 * (float)x0[1] + pe1 * (float)x1[1];

    // ---- rotate pipeline registers (renamed under unroll) ----
    x0 = x0n; x1 = x1n; e0 = e0n; e1 = e1n; m1 = m1n;
    s0n = s0a; s1n = s1a; e0n = e0a; e1n = e1a; m1n = m1a;
  }

  float inv = 1.f / (s + 1e-16f);
  float2 bv = *(const float2*)&bc[c0];
  float v0 = acc0 * inv + bv.x;
  float v1 = acc1 * inv + bv.y;
  v0 = v0 > 0.f ? v0 : (__expf(v0) - 1.f);   // elu
  v1 = v1 > 0.f ? v1 : (__expf(v1) - 1.f);
  *(h2*)&out[(size_t)node * 128 + c0] = h2{(_Float16)v0, (_Float16)v1};
}

// R16 (H=1, layer 3): one node per wave. 4 edges/iter across four 16-lane
// groups (group = lane>>4), 2 channels/lane over HC=32. Wave-uniform loop
// bounds; per-lane coalesced metadata loads (4 consecutive slots); DPP
// row-reduce per group (DPP rows are exactly 16 lanes); one cross-group
// shfl_xor(16/32) reduce at the end. Dummy slots clamped to end-1, masked.
__global__ __launch_bounds__(256) void k2w1_kernel(
    const _Float16* __restrict__ xl, const _Float16* __restrict__ xr,
    const int* __restrict__ row_ptr, const int* __restrict__ csr_src,
    const _Float16* __restrict__ ea_csr, const float* __restrict__ we,
    const float* __restrict__ att, const float* __restrict__ bc,
    _Float16* __restrict__ out, int n) {
  int tid = threadIdx.x;
  int lane = tid & 63;
  int node = blockIdx.x * 4 + (tid >> 6);
  if (node >= n) return;
  int g = lane >> 4;             // edge group 0..3
  int c0 = (lane & 15) << 1;     // 2 channels of HC=32

  int start = __builtin_amdgcn_readfirstlane(row_ptr[node]);
  int end   = __builtin_amdgcn_readfirstlane(row_ptr[node + 1]);   // len >= 1
  int last = end - 1;            // self-loop slot (valid dummy target)
  int iters = (end - start + 3) >> 2;

  // ---- prologue: iter0 metadata (longest latency first) ----
  int j0 = start + g;
  int ks = (j0 < end) ? j0 : last;
  float m = (j0 < end) ? 1.f : 0.f;
  int sp = csr_src[ks];                         // per-lane, 16B coalesced
  h8 e = *(const h8*)&ea_csr[(size_t)ks * 8];   // per-lane, 4x16B coalesced

  // per-lane tables (overlap the loads above)
  h2 w2[8];
#pragma unroll
  for (int k = 0; k < 8; k++) {
    float2 v = *(const float2*)&we[k * 32 + c0];
    w2[k] = h2{(_Float16)v.x, (_Float16)v.y};
  }
  const float LOG2E = 1.44269504088896f;
  float2 av = *(const float2*)&att[c0];
  h2 a2 = h2{(_Float16)(av.x * LOG2E), (_Float16)(av.y * LOG2E)};
  h2 xr2 = *(const h2*)&xr[(size_t)node * 32 + c0];
  const h2 p2 = h2{(_Float16)0.2f, (_Float16)0.2f};

  h2 xv = *(const h2*)&xl[(uint32_t)sp * 32u + (uint32_t)c0];

  float s = 0.f, acc0 = 0.f, acc1 = 0.f;

#pragma unroll 2
  for (int p = 0; p < iters; p++) {
    // ---- prefetch iter p+1 metadata ----
    int jn = start + 4 * (p + 1) + g;
    int kn = (jn < end) ? jn : last;
    float mn = (jn < end) ? 1.f : 0.f;
    int spn = csr_src[kn];
    h8 en = *(const h8*)&ea_csr[(size_t)kn * 8];

    // ---- compute current edge (per group) ----
    h2 t = xv + xr2;
#pragma unroll
    for (int k = 0; k < 8; k++) t += h2{e[k], e[k]} * w2[k];
    t = __builtin_elementwise_max(t, t * p2);
    float part = hdot2(t, a2, 0.f);

    // prefetch next xl gather (index just arrived)
    h2 xvn = *(const h2*)&xl[(uint32_t)spn * 32u + (uint32_t)c0];

    // 16-lane row reduce (per group, pure VALU)
    part = dppadd<0xB1>(part);
    part = dppadd<0x4E>(part);
    part = dppadd<0x141>(part);
    part = dppadd<0x140>(part);
    float pe = __builtin_amdgcn_exp2f(part) * m;
    s += pe;
    acc0 += pe * (float)xv[0];
    acc1 += pe * (float)xv[1];

    // rotate
    xv = xvn; e = en; m = mn;
  }

  // ---- cross-group reduce (once per node) ----
  s    += __shfl_xor(s, 16, 64);    s    += __shfl_xor(s, 32, 64);
  acc0 += __shfl_xor(acc0, 16, 64); acc0 += __shfl_xor(acc0, 32, 64);
  acc1 += __shfl_xor(acc1, 16, 64); acc1 += __shfl_xor(acc1, 32, 64);

  if (g == 0) {
    float inv = 1.f / (s + 1e-16f);
    float2 bv = *(const float2*)&bc[c0];
    float v0 = acc0 * inv + bv.x;
    float v1 = acc1 * inv + bv.y;
    v0 = v0 > 0.f ? v0 : (__expf(v0) - 1.f);   // elu
    v1 = v1 > 0.f ? v1 : (__expf(v1) - 1.f);
    *(h2*)&out[(size_t)node * 32 + c0] = h2{(_Float16)v0, (_Float16)v1};
  }
}

// ---------------------------------------------------------------- fused pooling + MLP
// block g: mean over graph g's node range -> fc1 (elu) -> fc2 -> out. gmean
// stays in LDS. R12: h2-vectorized accumulation (16 rowgroups x 16 ch-pairs).
__global__ __launch_bounds__(256) void poolfc_kernel(const _Float16* __restrict__ h,
                                                     const int* __restrict__ gstart,
                                                     const float* __restrict__ w1,
                                                     const float* __restrict__ b1,
                                                     const float* __restrict__ w2,
                                                     const float* __restrict__ b2,
                                                     float* __restrict__ out) {
  __shared__ float redx[256];
  __shared__ float redy[256];
  __shared__ float g[32];
  __shared__ float a1[64];
  int gi = blockIdx.x;
  int t = threadIdx.x;
  int s = gstart[gi], e = gstart[gi + 1];
  int cp = t & 15, rg = t >> 4;   // t = rg*16 + cp
  float ax = 0.f, ay = 0.f;
  for (int i = s + rg; i < e; i += 16) {
    h2 v = *(const h2*)&h[(size_t)i * 32 + cp * 2];
    ax += (float)v[0]; ay += (float)v[1];
  }
  redx[t] = ax; redy[t] = ay;
  __syncthreads();
  if (t < 128) { redx[t] += redx[t + 128]; redy[t] += redy[t + 128]; }
  __syncthreads();
  if (t < 64) { redx[t] += redx[t + 64]; redy[t] += redy[t + 64]; }
  __syncthreads();
  if (t < 32) { redx[t] += redx[t + 32]; redy[t] += redy[t + 32]; }
  __syncthreads();
  if (t < 16) {
    float inv = 1.f / fmaxf((float)(e - s), 1.f);
    g[2 * t]     = (redx[t] + redx[t + 16]) * inv;
    g[2 * t + 1] = (redy[t] + redy[t + 16]) * inv;
  }
  __syncthreads();
  if (t < 64) {
    float v = b1[t];
    for (int k = 0; k < 32; k++) v += g[k] * w1[k * 64 + t];
    a1[t] = v > 0.f ? v : (__expf(v) - 1.f);
  }
  __syncthreads();
  if (t < 4) {
    float o = b2[t];
    for (int k = 0; k < 64; k++) o += a1[k] * w2[k * 4 + t];
    out[gi * 4 + t] = o;
  }
}

// ---------------------------------------------------------------- launch

extern "C" void kernel_launch(void* const* d_in, const int* in_sizes, int n_in,
                              void* d_out, int out_size, void* d_ws, size_t ws_size,
                              hipStream_t stream) {
  const float* x     = (const float*)d_in[0];
  const int*   ei    = (const int*)d_in[1];
  const float* eattr = (const float*)d_in[2];
  const int*   batch = (const int*)d_in[3];
  const float *wl1 = (const float*)d_in[4],  *bl1 = (const float*)d_in[5];
  const float *wr1 = (const float*)d_in[6],  *br1 = (const float*)d_in[7];
  const float *we1 = (const float*)d_in[8],  *at1 = (const float*)d_in[9];
  const float *bc1 = (const float*)d_in[10];
  const float *wl2 = (const float*)d_in[11], *bl2 = (const float*)d_in[12];
  const float *wr2 = (const float*)d_in[13], *br2 = (const float*)d_in[14];
  const float *we2 = (const float*)d_in[15], *at2 = (const float*)d_in[16];
  const float *bc2 = (const float*)d_in[17];
  const float *wl3 = (const float*)d_in[18], *bl3 = (const float*)d_in[19];
  const float *wr3 = (const float*)d_in[20], *br3 = (const float*)d_in[21];
  const float *we3 = (const float*)d_in[22], *at3 = (const float*)d_in[23];
  const float *bc3 = (const float*)d_in[24];
  const float *wf1 = (const float*)d_in[25], *bf1 = (const float*)d_in[26];
  const float *wf2 = (const float*)d_in[27], *bf2 = (const float*)d_in[28];

  int N = in_sizes[0] / 16;
  int E = in_sizes[1] / 2;
  const int* srcp = ei;
  const int* dstp = ei + E;
  int EA = E + N;             // CSR entries incl. self-loops
  int NB = (N + 511) / 512;   // scan blocks (<=1024)

  char* wsb = (char*)d_ws;
  size_t off = 0;
  auto alloc = [&](size_t bytes) -> char* {
    char* p = wsb + off;
    off += (bytes + 255) & ~(size_t)255;
    return p;
  };
  int*       cnt     = (int*)alloc((size_t)N * 4);
  int*       row_ptr = (int*)alloc((size_t)(N + 1) * 4);
  int*       rank    = (int*)alloc((size_t)E * 4);
  int*       bpart   = (int*)alloc((size_t)1024 * 4);
  int*       boff    = (int*)alloc((size_t)1024 * 4);
  int*       csr_src = (int*)alloc((size_t)EA * 4);
  _Float16*  ea_csr  = (_Float16*)alloc((size_t)EA * 8 * 2);
  _Float16*  xl      = (_Float16*)alloc((size_t)N * 128 * 2);
  _Float16*  xr      = (_Float16*)alloc((size_t)N * 128 * 2);
  _Float16*  h16     = (_Float16*)alloc((size_t)N * 128 * 2);
  _Float16*  h3      = (_Float16*)alloc((size_t)N * 32 * 2);
  int*       gstart  = (int*)alloc((size_t)(GNUM + 1) * 4);
  _Float16*  wp1l    = (_Float16*)alloc((size_t)32 * 128 * 2);
  _Float16*  wp1r    = (_Float16*)alloc((size_t)32 * 128 * 2);
  _Float16*  wp2l    = (_Float16*)alloc((size_t)128 * 128 * 2);
  _Float16*  wp2r    = (_Float16*)alloc((size_t)128 * 128 * 2);
  _Float16*  wp3l    = (_Float16*)alloc((size_t)128 * 32 * 2);
  _Float16*  wp3r    = (_Float16*)alloc((size_t)128 * 32 * 2);

  hipMemsetAsync(cnt, 0, (size_t)N * 4, stream);

  rank_hist_kernel<<<(E + 255) / 256, 256, 0, stream>>>(dstp, cnt, rank, E);
  scan_part_kernel<<<NB, 256, 0, stream>>>(cnt, bpart, N);
  scan_top_kernel<<<1, 1024, 0, stream>>>(bpart, boff, row_ptr, batch, gstart, NB, N);
  scan_write_kernel<<<NB, 256, 0, stream>>>(cnt, boff, row_ptr, N);
  place_kernel<<<(E + 255) / 256, 256, 0, stream>>>(srcp, dstp, rank, row_ptr, eattr,
                                                    csr_src, ea_csr, E);
  selfloop_kernel<<<(N * 8 + 255) / 256, 256, 0, stream>>>(row_ptr, csr_src, ea_csr, N);
  pack_all_kernel<<<dim3(8, 6), 256, 0, stream>>>(wl1, wp1l, wr1, wp1r,
                                                  wl2, wp2l, wr2, wp2r,
                                                  wl3, wp3l, wr3, wp3r);

  // layer 1: K=16 -> 128 (fused L+R fp16 MFMA, K zero-padded to 32, f32 input)
  k1m16f_kernel<128><<<(N + 63) / 64, 256, 0, stream>>>(
      x, wp1l, bl1, xl, wp1r, br1, xr, N);
  k2w_kernel<<<(N + 3) / 4, 256, 0, stream>>>(xl, xr, row_ptr, csr_src, ea_csr,
                                              we1, at1, bc1, h16, N);
  // layer 2: K=128 -> 128 (fused L+R fp16 MFMA)
  k1mf_kernel<128, 128><<<(N + 63) / 64, 256, 0, stream>>>(
      h16, wp2l, bl2, xl, wp2r, br2, xr, N);
  k2w_kernel<<<(N + 3) / 4, 256, 0, stream>>>(xl, xr, row_ptr, csr_src, ea_csr,
                                              we2, at2, bc2, h16, N);
  // layer 3: K=128 -> 32 (fused L+R fp16 MFMA, single head)
  k1mf_kernel<128, 32><<<(N + 63) / 64, 256, 0, stream>>>(
      h16, wp3l, bl3, xl, wp3r, br3, xr, N);
  k2w1_kernel<<<(N + 3) / 4, 256, 0, stream>>>(xl, xr, row_ptr, csr_src, ea_csr,
                                               we3, at3, bc3, h3, N);

  poolfc_kernel<<<GNUM, 256, 0, stream>>>(h3, gstart, wf1, bf1, wf2, bf2, (float*)d_out);
}

// Round 8
// 665.582 us; speedup vs baseline: 1.0564x; 1.0564x over previous
//
#include <hip/hip_runtime.h>
#include <cstdint>
#include <type_traits>

// GNN GATv2 x3 + mean-pool + MLP.
// All GEMMs on fp16 MFMA; fp16 tables; fp16 CSR edge features (self-loop =
// last CSR entry). R18: revert R16's two regressions (GEMM fusion cost
// occupancy for L3-cheap A-reads; k2w1 inflated per-edge overhead) back to
// R15's unfused k1m/k1m16 + k2<1>. New: k2w pipeline DEEPENED -- metadata
// prefetch at distance 3, xl gathers at distance 2 (was 2/1): ea_csr and
// xl are L3-served (~600cy), old distances covered only ~100-160cy. +24
// VGPR (16->~60), still full occupancy. CSR build = R15 (rank_hist +
// atomic-free place).
constexpr int GNUM = 128;   // graphs

typedef _Float16 h2 __attribute__((ext_vector_type(2)));
typedef _Float16 h4 __attribute__((ext_vector_type(4)));
typedef _Float16 h8 __attribute__((ext_vector_type(8)));
typedef float f4 __attribute__((ext_vector_type(4)));

// v += dpp_shuffle<CTRL>(v) -- pure-VALU cross-lane add (no DS pipe).
// 0xB1 quad_perm[1,0,3,2] (xor1), 0x4E quad_perm[2,3,0,1] (xor2),
// 0x141 row_half_mirror (xor4-equiv once quads uniform),
// 0x140 row_mirror (xor8-equiv once octs uniform). DPP rows = 16 lanes.
template <int CTRL>
__device__ __forceinline__ float dppadd(float v) {
  union U { float f; int i; };
  U u, r;
  u.f = v;
  r.i = __builtin_amdgcn_update_dpp(0, u.i, CTRL, 0xF, 0xF, true);
  return v + r.f;
}

__device__ __forceinline__ float hdot2(h2 a, h2 b, float c) {
#if __has_builtin(__builtin_amdgcn_fdot2)
  return __builtin_amdgcn_fdot2(a, b, c, false);
#else
  return c + (float)a[0] * (float)b[0] + (float)a[1] * (float)b[1];
#endif
}

// ---------------------------------------------------------------- setup kernels

// R15: histogram + rank in one atomic pass. The atomic's return value is
// this edge's rank among edges sharing its dst (order arbitrary but unique).
__global__ __launch_bounds__(256) void rank_hist_kernel(const int* __restrict__ dst,
                                                        int* __restrict__ cnt,
                                                        int* __restrict__ rank, int E) {
  int i = blockIdx.x * 256 + threadIdx.x;
  if (i >= E) return;
  rank[i] = atomicAdd(&cnt[dst[i]], 1);
}

// ---- 3-phase parallel exclusive scan of (cnt[i]+1), 512 elems per block ----
__global__ __launch_bounds__(256) void scan_part_kernel(const int* __restrict__ cnt,
                                                        int* __restrict__ bpart, int n) {
  __shared__ int red[256];
  int base = blockIdx.x * 512;
  int t = threadIdx.x;
  int s = 0;
  int i0 = base + t, i1 = base + 256 + t;
  if (i0 < n) s += cnt[i0] + 1;
  if (i1 < n) s += cnt[i1] + 1;
  red[t] = s;
  __syncthreads();
  for (int off = 128; off > 0; off >>= 1) {
    if (t < off) red[t] += red[t + off];
    __syncthreads();
  }
  if (t == 0) bpart[blockIdx.x] = red[0];
}

// scan of block partials + (fused) graph-boundary binary search
__global__ __launch_bounds__(1024) void scan_top_kernel(const int* __restrict__ bpart,
                                                        int* __restrict__ boff,
                                                        int* __restrict__ row_ptr,
                                                        const int* __restrict__ batch,
                                                        int* __restrict__ gstart,
                                                        int B, int n) {
  __shared__ int buf[1024];
  int t = threadIdx.x;
  buf[t] = (t < B) ? bpart[t] : 0;
  __syncthreads();
  for (int off = 1; off < 1024; off <<= 1) {
    int v = (t >= off) ? buf[t - off] : 0;
    __syncthreads();
    buf[t] += v;
    __syncthreads();
  }
  if (t < B) boff[t] = (t == 0) ? 0 : buf[t - 1];
  if (t == 0) row_ptr[n] = buf[1023];
  // fused gbound: graph g's node range start (batch is sorted)
  if (t <= GNUM) {
    int lo = 0, hi = n;
    while (lo < hi) {
      int mid = (lo + hi) >> 1;
      if (batch[mid] < t) lo = mid + 1; else hi = mid;
    }
    gstart[t] = lo;
  }
}

// writes row_ptr (exclusive prefix of cnt[i]+1)
__global__ __launch_bounds__(256) void scan_write_kernel(const int* __restrict__ cnt,
                                                         const int* __restrict__ boff,
                                                         int* __restrict__ row_ptr, int n) {
  __shared__ int red[256];
  int base = blockIdx.x * 512;
  int t = threadIdx.x;
  int i0 = base + 2 * t, i1 = base + 2 * t + 1;
  int v0 = (i0 < n) ? cnt[i0] + 1 : 0;
  int v1 = (i1 < n) ? cnt[i1] + 1 : 0;
  int val = v0 + v1;
  red[t] = val;
  __syncthreads();
  for (int off = 1; off < 256; off <<= 1) {
    int u = (t >= off) ? red[t - off] : 0;
    __syncthreads();
    red[t] += u;
    __syncthreads();
  }
  int o = boff[blockIdx.x] + red[t] - val;   // exclusive prefix for this pair
  if (i0 < n) row_ptr[i0] = o;
  if (i1 < n) row_ptr[i1] = o + v0;
}

// R15: ATOMIC-FREE placement. slot = row_ptr[dst] + rank (unique, < self
// slot). Sequential reads, fire-and-forget random stores.
__global__ __launch_bounds__(256) void place_kernel(const int* __restrict__ src,
                                                    const int* __restrict__ dst,
                                                    const int* __restrict__ rank,
                                                    const int* __restrict__ row_ptr,
                                                    const float* __restrict__ ea,
                                                    int* __restrict__ csr_src,
                                                    _Float16* __restrict__ ea_csr, int E) {
  int i = blockIdx.x * 256 + threadIdx.x;
  if (i >= E) return;
  int d = dst[i];
  int p = row_ptr[d] + rank[i];
  csr_src[p] = src[i];
  float4 e0 = *(const float4*)&ea[(size_t)i * 8];
  float4 e1 = *(const float4*)&ea[(size_t)i * 8 + 4];
  h8 v;
  v[0] = (_Float16)e0.x; v[1] = (_Float16)e0.y; v[2] = (_Float16)e0.z; v[3] = (_Float16)e0.w;
  v[4] = (_Float16)e1.x; v[5] = (_Float16)e1.y; v[6] = (_Float16)e1.z; v[7] = (_Float16)e1.w;
  *(h8*)&ea_csr[(size_t)p * 8] = v;
}

// fill self-loop slot (last of each segment) with segment-mean attrs.
// 8 threads per node (one per edge channel).
__global__ __launch_bounds__(256) void selfloop_kernel(const int* __restrict__ row_ptr,
                                                       int* __restrict__ csr_src,
                                                       _Float16* __restrict__ ea_csr, int n) {
  int idx = blockIdx.x * 256 + threadIdx.x;
  int i = idx >> 3, c = idx & 7;
  if (i >= n) return;
  int s = row_ptr[i], e = row_ptr[i + 1] - 1;   // [s,e) real edges, e = self slot
  float a = 0.f;
  for (int j = s; j < e; j++) a += (float)ea_csr[(size_t)j * 8 + c];
  float inv = 1.f / fmaxf((float)(e - s), 1.f);
  ea_csr[(size_t)e * 8 + c] = (_Float16)(a * inv);
  if (c == 0) csr_src[e] = i;
}

// pack all 6 weight matrices f32 -> fp16 MFMA B-fragment order in one launch.
// blockIdx.y selects matrix; zero-pad K to Kpad.
__global__ __launch_bounds__(256) void pack_all_kernel(
    const float* __restrict__ wl1, _Float16* __restrict__ p1l,
    const float* __restrict__ wr1, _Float16* __restrict__ p1r,
    const float* __restrict__ wl2, _Float16* __restrict__ p2l,
    const float* __restrict__ wr2, _Float16* __restrict__ p2r,
    const float* __restrict__ wl3, _Float16* __restrict__ p3l,
    const float* __restrict__ wr3, _Float16* __restrict__ p3r) {
  int y = blockIdx.y;
  const float* w; _Float16* wp; int Kreal, Kpad, NC;
  switch (y) {
    case 0: w = wl1; wp = p1l; Kreal = 16;  Kpad = 32;  NC = 128; break;
    case 1: w = wr1; wp = p1r; Kreal = 16;  Kpad = 32;  NC = 128; break;
    case 2: w = wl2; wp = p2l; Kreal = 128; Kpad = 128; NC = 128; break;
    case 3: w = wr2; wp = p2r; Kreal = 128; Kpad = 128; NC = 128; break;
    case 4: w = wl3; wp = p3l; Kreal = 128; Kpad = 128; NC = 32;  break;
    default: w = wr3; wp = p3r; Kreal = 128; Kpad = 128; NC = 32; break;
  }
  int KB = Kpad / 32;
  int total = (NC / 16) * KB * 64;
  int idx = blockIdx.x * 256 + threadIdx.x;
  if (idx >= total) return;
  int lane = idx & 63;
  int blk = idx >> 6;
  int nt = blk / KB, kb = blk % KB;
  int col = nt * 16 + (lane & 15);
  int krow = kb * 32 + (lane >> 4) * 8;
  h8 v;
#pragma unroll
  for (int j = 0; j < 8; j++)
    v[j] = (krow + j < Kreal) ? (_Float16)w[(size_t)(krow + j) * NC + col] : (_Float16)0.f;
  *(h8*)&wp[(size_t)idx * 8] = v;
}

// ---------------------------------------------------------------- node transform GEMMs

// fp16 MFMA, K=128. 256 thr = 4 waves, 16 nodes/wave, 64 nodes/block.
// (R15 unfused form: gridDim.y selects L/R; A re-read is L3-cheap.)
template <int K, int NCOLS>
__global__ __launch_bounds__(256) void k1m_kernel(const _Float16* __restrict__ x,
                                                  const _Float16* __restrict__ wp0,
                                                  const float* __restrict__ b0,
                                                  _Float16* __restrict__ out0,
                                                  const _Float16* __restrict__ wp1,
                                                  const float* __restrict__ b1,
                                                  _Float16* __restrict__ out1, int n) {
  constexpr int NT = NCOLS / 16, KB = K / 32;
  const _Float16* wp = blockIdx.y ? wp1 : wp0;
  const float* b = blockIdx.y ? b1 : b0;
  _Float16* out = blockIdx.y ? out1 : out0;

  int tid = threadIdx.x;
  int wave = tid >> 6, lane = tid & 63;
  int m = lane & 15, quad = lane >> 4;
  int node0 = blockIdx.x * 64 + wave * 16;

  h8 afrag[KB];
  int anode = node0 + m;
  if (anode < n) {
#pragma unroll
    for (int kb = 0; kb < KB; kb++)
      afrag[kb] = *(const h8*)&x[(size_t)anode * K + kb * 32 + quad * 8];
  } else {
#pragma unroll
    for (int kb = 0; kb < KB; kb++) afrag[kb] = (h8)(_Float16)0.f;
  }

  f4 acc[NT] = {};
#pragma unroll
  for (int nt = 0; nt < NT; nt++) {
#pragma unroll
    for (int kb = 0; kb < KB; kb++) {
      h8 bfrag = *(const h8*)&wp[((size_t)(nt * KB + kb) * 64 + lane) * 8];
      acc[nt] = __builtin_amdgcn_mfma_f32_16x16x32_f16(afrag[kb], bfrag, acc[nt], 0, 0, 0);
    }
  }

#pragma unroll
  for (int nt = 0; nt < NT; nt++) {
#pragma unroll
    for (int r = 0; r < 4; r++) {
      int row = node0 + quad * 4 + r;
      if (row < n) {
        int col = nt * 16 + m;
        out[(size_t)row * NCOLS + col] = (_Float16)(acc[nt][r] + b[col]);
      }
    }
  }
}

// fp16 MFMA, Kreal=16 zero-padded to 32 (layer 1); reads f32 x directly and
// converts in-register.
template <int NCOLS>
__global__ __launch_bounds__(256) void k1m16_kernel(const float* __restrict__ x,
                                                    const _Float16* __restrict__ wp0,
                                                    const float* __restrict__ b0,
                                                    _Float16* __restrict__ out0,
                                                    const _Float16* __restrict__ wp1,
                                                    const float* __restrict__ b1,
                                                    _Float16* __restrict__ out1, int n) {
  constexpr int NT = NCOLS / 16;
  const _Float16* wp = blockIdx.y ? wp1 : wp0;
  const float* b = blockIdx.y ? b1 : b0;
  _Float16* out = blockIdx.y ? out1 : out0;

  int tid = threadIdx.x;
  int wave = tid >> 6, lane = tid & 63;
  int m = lane & 15, quad = lane >> 4;
  int node0 = blockIdx.x * 64 + wave * 16;

  int anode = node0 + m;
  h8 afrag = (h8)(_Float16)0.f;
  if (anode < n && quad < 2) {
    float4 v0 = *(const float4*)&x[(size_t)anode * 16 + quad * 8];
    float4 v1 = *(const float4*)&x[(size_t)anode * 16 + quad * 8 + 4];
    afrag[0] = (_Float16)v0.x; afrag[1] = (_Float16)v0.y;
    afrag[2] = (_Float16)v0.z; afrag[3] = (_Float16)v0.w;
    afrag[4] = (_Float16)v1.x; afrag[5] = (_Float16)v1.y;
    afrag[6] = (_Float16)v1.z; afrag[7] = (_Float16)v1.w;
  }

  f4 acc[NT] = {};
#pragma unroll
  for (int nt = 0; nt < NT; nt++) {
    h8 bfrag = *(const h8*)&wp[((size_t)nt * 64 + lane) * 8];
    acc[nt] = __builtin_amdgcn_mfma_f32_16x16x32_f16(afrag, bfrag, acc[nt], 0, 0, 0);
  }

#pragma unroll
  for (int nt = 0; nt < NT; nt++) {
#pragma unroll
    for (int r = 0; r < 4; r++) {
      int row = node0 + quad * 4 + r;
      if (row < n) {
        int col = nt * 16 + m;
        out[(size_t)row * NCOLS + col] = (_Float16)(acc[nt][r] + b[col]);
      }
    }
  }
}

// ---------------------------------------------------------------- fused GATv2 edge+softmax+aggregate
// R18 (H=4): one node per wave, 64 lanes x 2 channels; scalar-pipe edge
// metadata. DEEP 4-slot pipeline per iteration:
//   A: idx+ea loads for pair p+3     (3 iters of latency cover, ~L3 depth)
//   B: xl gathers for pair p+2       (2 iters of cover; indices from slot2)
//   C: compute pair p                (DPP reduce, fdot2, masked edge1)
// One-pass softmax (no max-shift; logits O(1)); att pre-scaled by log2(e).
__global__ __launch_bounds__(256) void k2w_kernel(
    const _Float16* __restrict__ xl, const _Float16* __restrict__ xr,
    const int* __restrict__ row_ptr, const int* __restrict__ csr_src,
    const _Float16* __restrict__ ea_csr, const float* __restrict__ we,
    const float* __restrict__ att, const float* __restrict__ bc,
    _Float16* __restrict__ out, int n) {
  int tid = threadIdx.x;
  int lane = tid & 63;
  int node = blockIdx.x * 4 + (tid >> 6);
  if (node >= n) return;
  int c0 = lane << 1;          // 2 channels per lane; head = lane>>4

  int start = __builtin_amdgcn_readfirstlane(row_ptr[node]);
  int end   = __builtin_amdgcn_readfirstlane(row_ptr[node + 1]);   // len >= 1 (self loop)
  int pairs = (end - start + 1) >> 1;

  // clamped metadata loader for pair index p_ (edges start+2p_, +1).
  // Within the compute range, edge0 is always valid; only edge1 may be a
  // dummy (mask mm). Prefetch slots beyond `pairs` clamp to start (valid).
  auto ldmeta = [&](int p_, int& sa, int& sb, h8& ea_, h8& eb, float& mm) {
    int j = start + 2 * p_;
    int k0 = (j < end) ? j : start;
    int k1 = (j + 1 < end) ? j + 1 : k0;
    mm = (j + 1 < end) ? 1.f : 0.f;
    sa = __builtin_amdgcn_readfirstlane(csr_src[k0]);
    sb = __builtin_amdgcn_readfirstlane(csr_src[k1]);
    ea_ = *(const h8*)&ea_csr[(size_t)k0 * 8];
    eb  = *(const h8*)&ea_csr[(size_t)k1 * 8];
  };

  // ---- prologue: slots 0,1,2 metadata (longest latency first) ----
  int s0a, s0b, s1a, s1b, s2a, s2b;
  h8 e0a, e0b, e1a, e1b, e2a, e2b;
  float m0, m1, m2;
  ldmeta(0, s0a, s0b, e0a, e0b, m0);
  ldmeta(1, s1a, s1b, e1a, e1b, m1);
  ldmeta(2, s2a, s2b, e2a, e2b, m2);

  // per-lane tables (independent work overlapping the loads above)
  h2 w2[8];
#pragma unroll
  for (int k = 0; k < 8; k++) {
    float2 v = *(const float2*)&we[k * 128 + c0];
    w2[k] = h2{(_Float16)v.x, (_Float16)v.y};
  }
  const float LOG2E = 1.44269504088896f;
  float2 av = *(const float2*)&att[c0];
  h2 a2 = h2{(_Float16)(av.x * LOG2E), (_Float16)(av.y * LOG2E)};
  h2 xr2 = *(const h2*)&xr[(size_t)node * 128 + c0];
  const h2 p2 = h2{(_Float16)0.2f, (_Float16)0.2f};

  // prologue gathers: pairs 0 and 1
  h2 x0a = *(const h2*)&xl[(uint32_t)s0a * 128u + (uint32_t)c0];
  h2 x0b = *(const h2*)&xl[(uint32_t)s0b * 128u + (uint32_t)c0];
  h2 x1a = *(const h2*)&xl[(uint32_t)s1a * 128u + (uint32_t)c0];
  h2 x1b = *(const h2*)&xl[(uint32_t)s1b * 128u + (uint32_t)c0];

  float s = 0.f, acc0 = 0.f, acc1 = 0.f;

#pragma unroll 2
  for (int p = 0; p < pairs; p++) {
    // ---- stage A: metadata for pair p+3 ----
    int s3a, s3b; h8 e3a, e3b; float m3;
    ldmeta(p + 3, s3a, s3b, e3a, e3b, m3);

    // ---- stage B: xl gathers for pair p+2 (indices resident 1 iter) ----
    h2 x2a = *(const h2*)&xl[(uint32_t)s2a * 128u + (uint32_t)c0];
    h2 x2b = *(const h2*)&xl[(uint32_t)s2b * 128u + (uint32_t)c0];

    // ---- stage C: compute pair p ----
    h2 t0 = x0a + xr2;
    h2 t1 = x0b + xr2;
#pragma unroll
    for (int k = 0; k < 8; k++) {
      t0 += h2{e0a[k], e0a[k]} * w2[k];
      t1 += h2{e0b[k], e0b[k]} * w2[k];
    }
    t0 = __builtin_elementwise_max(t0, t0 * p2);
    t1 = __builtin_elementwise_max(t1, t1 * p2);
    float part0 = hdot2(t0, a2, 0.f);
    float part1 = hdot2(t1, a2, 0.f);
    // 16-lane head reduce, pure VALU (DPP)
    part0 = dppadd<0xB1>(part0);   part1 = dppadd<0xB1>(part1);
    part0 = dppadd<0x4E>(part0);   part1 = dppadd<0x4E>(part1);
    part0 = dppadd<0x141>(part0);  part1 = dppadd<0x141>(part1);
    part0 = dppadd<0x140>(part0);  part1 = dppadd<0x140>(part1);
    float pe0 = __builtin_amdgcn_exp2f(part0);
    float pe1 = __builtin_amdgcn_exp2f(part1) * m0;   // mask dummy edge1
    s += pe0 + pe1;
    acc0 += pe0 * (float)x0a[0] + pe1 * (float)x0b[0];
    acc1 += pe0 * (float)x0a[1] + pe1 * (float)x0b[1];

    // ---- rotate pipeline slots (renamed under unroll) ----
    x0a = x1a; x0b = x1b; x1a = x2a; x1b = x2b;
    e0a = e1a; e0b = e1b; e1a = e2a; e1b = e2b; e2a = e3a; e2b = e3b;
    m0 = m1; m1 = m2; m2 = m3;
    s2a = s3a; s2b = s3b;
  }

  float inv = 1.f / (s + 1e-16f);
  float2 bv = *(const float2*)&bc[c0];
  float v0 = acc0 * inv + bv.x;
  float v1 = acc1 * inv + bv.y;
  v0 = v0 > 0.f ? v0 : (__expf(v0) - 1.f);   // elu
  v1 = v1 > 0.f ? v1 : (__expf(v1) - 1.f);
  *(h2*)&out[(size_t)node * 128 + c0] = h2{(_Float16)v0, (_Float16)v1};
}

// H=1 path (layer 3): R7 2-wide pipeline, 8 lanes/node + DPP/fdot2
// (R15 form; R16's one-node-per-wave port inflated per-edge overhead).
template <int H>
__global__ __launch_bounds__(128) void k2_kernel(
    const _Float16* __restrict__ xl, const _Float16* __restrict__ xr,
    const int* __restrict__ row_ptr, const int* __restrict__ csr_src,
    const _Float16* __restrict__ ea_csr, const float* __restrict__ we,
    const float* __restrict__ att, const float* __restrict__ bc,
    _Float16* __restrict__ out, int n) {
  constexpr int HC = H * 32;
  constexpr int NL = HC / 4;   // lanes per node (8)
  constexpr int NPB = 128 / NL;

  int tid = threadIdx.x;
  int ln = tid / NL, q = tid % NL;
  int c0 = 4 * q;
  int node = blockIdx.x * NPB + ln;
  if (node >= n) return;

  h2 w2[8][2];
#pragma unroll
  for (int k = 0; k < 8; k++) {
    float4 v = *(const float4*)&we[k * HC + c0];
    w2[k][0] = h2{(_Float16)v.x, (_Float16)v.y};
    w2[k][1] = h2{(_Float16)v.z, (_Float16)v.w};
  }
  const float LOG2E = 1.44269504088896f;
  float4 av = *(const float4*)&att[c0];
  h2 a0 = h2{(_Float16)(av.x * LOG2E), (_Float16)(av.y * LOG2E)};
  h2 a1 = h2{(_Float16)(av.z * LOG2E), (_Float16)(av.w * LOG2E)};
  h4 xrh = *(const h4*)&xr[(size_t)node * HC + c0];
  h2 xr0 = h2{xrh[0], xrh[1]}, xr1 = h2{xrh[2], xrh[3]};
  const h2 p2 = h2{(_Float16)0.2f, (_Float16)0.2f};

  float acc[4] = {0.f, 0.f, 0.f, 0.f};
  float s = 0.f;

  int start = row_ptr[node], end = row_ptr[node + 1];   // len >= 1 (self loop)
  int len = end - start;
  int pairs = (len + 1) >> 1;

  // prologue: load pair 0 (clamped)
  int j1 = (start + 1 < end) ? start + 1 : start;
  float m1 = (start + 1 < end) ? 1.f : 0.f;
  int s0 = csr_src[start], s1 = csr_src[j1];
  h8 e0 = *(const h8*)&ea_csr[(size_t)start * 8];
  h8 e1 = *(const h8*)&ea_csr[(size_t)j1 * 8];
  h4 x0 = *(const h4*)&xl[(size_t)s0 * HC + c0];
  h4 x1 = *(const h4*)&xl[(size_t)s1 * HC + c0];

#pragma unroll 2
  for (int p = 0; p < pairs; p++) {
    // ---- issue next pair's src/ea loads (clamped; unused garbage on last) ----
    int jn = start + 2 * (p + 1);
    int k0 = (jn < end) ? jn : start;
    int k1 = (jn + 1 < end) ? jn + 1 : k0;
    float nm1 = (jn + 1 < end) ? 1.f : 0.f;
    int ns0 = csr_src[k0], ns1 = csr_src[k1];
    h8 ne0 = *(const h8*)&ea_csr[(size_t)k0 * 8];
    h8 ne1 = *(const h8*)&ea_csr[(size_t)k1 * 8];

    // ---- logits for current pair (two independent chains) ----
    h2 t00 = h2{x0[0], x0[1]} + xr0;
    h2 t01 = h2{x0[2], x0[3]} + xr1;
    h2 t10 = h2{x1[0], x1[1]} + xr0;
    h2 t11 = h2{x1[2], x1[3]} + xr1;
#pragma unroll
    for (int k = 0; k < 8; k++) {
      h2 ev0 = h2{e0[k], e0[k]};
      h2 ev1 = h2{e1[k], e1[k]};
      t00 += ev0 * w2[k][0];
      t01 += ev0 * w2[k][1];
      t10 += ev1 * w2[k][0];
      t11 += ev1 * w2[k][1];
    }
    t00 = __builtin_elementwise_max(t00, t00 * p2);
    t01 = __builtin_elementwise_max(t01, t01 * p2);
    t10 = __builtin_elementwise_max(t10, t10 * p2);
    t11 = __builtin_elementwise_max(t11, t11 * p2);
    float part0 = hdot2(t00, a0, hdot2(t01, a1, 0.f));
    float part1 = hdot2(t10, a0, hdot2(t11, a1, 0.f));

    // ---- issue next pair's xl gathers before the reduce chain ----
    h4 nx0 = *(const h4*)&xl[(size_t)ns0 * HC + c0];
    h4 nx1 = *(const h4*)&xl[(size_t)ns1 * HC + c0];

    // ---- 8-lane reduce (DPP, pure VALU), exp, accumulate ----
    part0 = dppadd<0xB1>(part0);   part1 = dppadd<0xB1>(part1);
    part0 = dppadd<0x4E>(part0);   part1 = dppadd<0x4E>(part1);
    part0 = dppadd<0x141>(part0);  part1 = dppadd<0x141>(part1);
    float pe0 = __builtin_amdgcn_exp2f(part0);
    float pe1 = __builtin_amdgcn_exp2f(part1) * m1;
    s += pe0 + pe1;
#pragma unroll
    for (int i = 0; i < 4; i++)
      acc[i] += pe0 * (float)x0[i] + pe1 * (float)x1[i];

    // ---- rotate pipeline registers (renamed away under unroll) ----
    s0 = ns0; s1 = ns1; e0 = ne0; e1 = ne1; x0 = nx0; x1 = nx1; m1 = nm1;
  }

  float inv = 1.f / (s + 1e-16f);
  h4 o;
#pragma unroll
  for (int i = 0; i < 4; i++) {
    float v = acc[i] * inv + bc[c0 + i];
    o[i] = (_Float16)(v > 0.f ? v : (__expf(v) - 1.f));   // elu
  }
  *(h4*)&out[(size_t)node * HC + c0] = o;
}

// ---------------------------------------------------------------- fused pooling + MLP
// block g: mean over graph g's node range -> fc1 (elu) -> fc2 -> out. gmean
// stays in LDS. h2-vectorized accumulation (16 rowgroups x 16 ch-pairs).
__global__ __launch_bounds__(256) void poolfc_kernel(const _Float16* __restrict__ h,
                                                     const int* __restrict__ gstart,
                                                     const float* __restrict__ w1,
                                                     const float* __restrict__ b1,
                                                     const float* __restrict__ w2,
                                                     const float* __restrict__ b2,
                                                     float* __restrict__ out) {
  __shared__ float redx[256];
  __shared__ float redy[256];
  __shared__ float g[32];
  __shared__ float a1[64];
  int gi = blockIdx.x;
  int t = threadIdx.x;
  int s = gstart[gi], e = gstart[gi + 1];
  int cp = t & 15, rg = t >> 4;   // t = rg*16 + cp
  float ax = 0.f, ay = 0.f;
  for (int i = s + rg; i < e; i += 16) {
    h2 v = *(const h2*)&h[(size_t)i * 32 + cp * 2];
    ax += (float)v[0]; ay += (float)v[1];
  }
  redx[t] = ax; redy[t] = ay;
  __syncthreads();
  if (t < 128) { redx[t] += redx[t + 128]; redy[t] += redy[t + 128]; }
  __syncthreads();
  if (t < 64) { redx[t] += redx[t + 64]; redy[t] += redy[t + 64]; }
  __syncthreads();
  if (t < 32) { redx[t] += redx[t + 32]; redy[t] += redy[t + 32]; }
  __syncthreads();
  if (t < 16) {
    float inv = 1.f / fmaxf((float)(e - s), 1.f);
    g[2 * t]     = (redx[t] + redx[t + 16]) * inv;
    g[2 * t + 1] = (redy[t] + redy[t + 16]) * inv;
  }
  __syncthreads();
  if (t < 64) {
    float v = b1[t];
    for (int k = 0; k < 32; k++) v += g[k] * w1[k * 64 + t];
    a1[t] = v > 0.f ? v : (__expf(v) - 1.f);
  }
  __syncthreads();
  if (t < 4) {
    float o = b2[t];
    for (int k = 0; k < 64; k++) o += a1[k] * w2[k * 4 + t];
    out[gi * 4 + t] = o;
  }
}

// ---------------------------------------------------------------- launch

extern "C" void kernel_launch(void* const* d_in, const int* in_sizes, int n_in,
                              void* d_out, int out_size, void* d_ws, size_t ws_size,
                              hipStream_t stream) {
  const float* x     = (const float*)d_in[0];
  const int*   ei    = (const int*)d_in[1];
  const float* eattr = (const float*)d_in[2];
  const int*   batch = (const int*)d_in[3];
  const float *wl1 = (const float*)d_in[4],  *bl1 = (const float*)d_in[5];
  const float *wr1 = (const float*)d_in[6],  *br1 = (const float*)d_in[7];
  const float *we1 = (const float*)d_in[8],  *at1 = (const float*)d_in[9];
  const float *bc1 = (const float*)d_in[10];
  const float *wl2 = (const float*)d_in[11], *bl2 = (const float*)d_in[12];
  const float *wr2 = (const float*)d_in[13], *br2 = (const float*)d_in[14];
  const float *we2 = (const float*)d_in[15], *at2 = (const float*)d_in[16];
  const float *bc2 = (const float*)d_in[17];
  const float *wl3 = (const float*)d_in[18], *bl3 = (const float*)d_in[19];
  const float *wr3 = (const float*)d_in[20], *br3 = (const float*)d_in[21];
  const float *we3 = (const float*)d_in[22], *at3 = (const float*)d_in[23];
  const float *bc3 = (const float*)d_in[24];
  const float *wf1 = (const float*)d_in[25], *bf1 = (const float*)d_in[26];
  const float *wf2 = (const float*)d_in[27], *bf2 = (const float*)d_in[28];

  int N = in_sizes[0] / 16;
  int E = in_sizes[1] / 2;
  const int* srcp = ei;
  const int* dstp = ei + E;
  int EA = E + N;             // CSR entries incl. self-loops
  int NB = (N + 511) / 512;   // scan blocks (<=1024)

  char* wsb = (char*)d_ws;
  size_t off = 0;
  auto alloc = [&](size_t bytes) -> char* {
    char* p = wsb + off;
    off += (bytes + 255) & ~(size_t)255;
    return p;
  };
  int*       cnt     = (int*)alloc((size_t)N * 4);
  int*       row_ptr = (int*)alloc((size_t)(N + 1) * 4);
  int*       rank    = (int*)alloc((size_t)E * 4);
  int*       bpart   = (int*)alloc((size_t)1024 * 4);
  int*       boff    = (int*)alloc((size_t)1024 * 4);
  int*       csr_src = (int*)alloc((size_t)EA * 4);
  _Float16*  ea_csr  = (_Float16*)alloc((size_t)EA * 8 * 2);
  _Float16*  xl      = (_Float16*)alloc((size_t)N * 128 * 2);
  _Float16*  xr      = (_Float16*)alloc((size_t)N * 128 * 2);
  _Float16*  h16     = (_Float16*)alloc((size_t)N * 128 * 2);
  _Float16*  h3      = (_Float16*)alloc((size_t)N * 32 * 2);
  int*       gstart  = (int*)alloc((size_t)(GNUM + 1) * 4);
  _Float16*  wp1l    = (_Float16*)alloc((size_t)32 * 128 * 2);
  _Float16*  wp1r    = (_Float16*)alloc((size_t)32 * 128 * 2);
  _Float16*  wp2l    = (_Float16*)alloc((size_t)128 * 128 * 2);
  _Float16*  wp2r    = (_Float16*)alloc((size_t)128 * 128 * 2);
  _Float16*  wp3l    = (_Float16*)alloc((size_t)128 * 32 * 2);
  _Float16*  wp3r    = (_Float16*)alloc((size_t)128 * 32 * 2);

  hipMemsetAsync(cnt, 0, (size_t)N * 4, stream);

  rank_hist_kernel<<<(E + 255) / 256, 256, 0, stream>>>(dstp, cnt, rank, E);
  scan_part_kernel<<<NB, 256, 0, stream>>>(cnt, bpart, N);
  scan_top_kernel<<<1, 1024, 0, stream>>>(bpart, boff, row_ptr, batch, gstart, NB, N);
  scan_write_kernel<<<NB, 256, 0, stream>>>(cnt, boff, row_ptr, N);
  place_kernel<<<(E + 255) / 256, 256, 0, stream>>>(srcp, dstp, rank, row_ptr, eattr,
                                                    csr_src, ea_csr, E);
  selfloop_kernel<<<(N * 8 + 255) / 256, 256, 0, stream>>>(row_ptr, csr_src, ea_csr, N);
  pack_all_kernel<<<dim3(8, 6), 256, 0, stream>>>(wl1, wp1l, wr1, wp1r,
                                                  wl2, wp2l, wr2, wp2r,
                                                  wl3, wp3l, wr3, wp3r);

  // layer 1: K=16 -> 128 (fp16 MFMA, K zero-padded to 32, f32 input)
  k1m16_kernel<128><<<dim3((N + 63) / 64, 2), 256, 0, stream>>>(
      x, wp1l, bl1, xl, wp1r, br1, xr, N);
  k2w_kernel<<<(N + 3) / 4, 256, 0, stream>>>(xl, xr, row_ptr, csr_src, ea_csr,
                                              we1, at1, bc1, h16, N);
  // layer 2: K=128 -> 128 (fp16 MFMA)
  k1m_kernel<128, 128><<<dim3((N + 63) / 64, 2), 256, 0, stream>>>(
      h16, wp2l, bl2, xl, wp2r, br2, xr, N);
  k2w_kernel<<<(N + 3) / 4, 256, 0, stream>>>(xl, xr, row_ptr, csr_src, ea_csr,
                                              we2, at2, bc2, h16, N);
  // layer 3: K=128 -> 32 (fp16 MFMA, single head)
  k1m_kernel<128, 32><<<dim3((N + 63) / 64, 2), 256, 0, stream>>>(
      h16, wp3l, bl3, xl, wp3r, br3, xr, N);
  k2_kernel<1><<<(N + 15) / 16, 128, 0, stream>>>(xl, xr, row_ptr, csr_src, ea_csr,
                                                  we3, at3, bc3, h3, N);

  poolfc_kernel<<<GNUM, 256, 0, stream>>>(h3, gstart, wf1, bf1, wf2, bf2, (float*)d_out);
}

// Round 10
// 663.107 us; speedup vs baseline: 1.0603x; 1.0037x over previous
//
#include <hip/hip_runtime.h>
#include <cstdint>
#include <type_traits>

// GNN GATv2 x3 + mean-pool + MLP.
// All GEMMs on fp16 MFMA; fp16 tables; fp16 CSR edge features (self-loop =
// last CSR entry). R20 == R19 resubmit (container infra failure twice; same
// mode as R6->R7 which ran clean unchanged; place_x re-audited, no defect).
// R19: k2w reverted to R15 3-stage form (R18 deep pipeline was null).
// place -> place_x: XCD-sharded dst-windowed placement. Grid = chunks x 8;
// block bid handles chunk bid>>3, window bid&7 (N/8 dst range). With
// round-robin block->XCD dispatch each window's output region (~4MB) is
// written by ONE XCD only and stays L2-resident -> lines finalized in
// cache, written back once (was ~150MB random-store writeback, ~105us by
// cross-round subtraction). CSR build otherwise = R15 (rank_hist + scan).
constexpr int GNUM = 128;   // graphs

typedef _Float16 h2 __attribute__((ext_vector_type(2)));
typedef _Float16 h4 __attribute__((ext_vector_type(4)));
typedef _Float16 h8 __attribute__((ext_vector_type(8)));
typedef float f4 __attribute__((ext_vector_type(4)));

// v += dpp_shuffle<CTRL>(v) -- pure-VALU cross-lane add (no DS pipe).
// 0xB1 quad_perm[1,0,3,2] (xor1), 0x4E quad_perm[2,3,0,1] (xor2),
// 0x141 row_half_mirror (xor4-equiv once quads uniform),
// 0x140 row_mirror (xor8-equiv once octs uniform). DPP rows = 16 lanes.
template <int CTRL>
__device__ __forceinline__ float dppadd(float v) {
  union U { float f; int i; };
  U u, r;
  u.f = v;
  r.i = __builtin_amdgcn_update_dpp(0, u.i, CTRL, 0xF, 0xF, true);
  return v + r.f;
}

__device__ __forceinline__ float hdot2(h2 a, h2 b, float c) {
#if __has_builtin(__builtin_amdgcn_fdot2)
  return __builtin_amdgcn_fdot2(a, b, c, false);
#else
  return c + (float)a[0] * (float)b[0] + (float)a[1] * (float)b[1];
#endif
}

// ---------------------------------------------------------------- setup kernels

// R15: histogram + rank in one atomic pass. The atomic's return value is
// this edge's rank among edges sharing its dst (order arbitrary but unique).
__global__ __launch_bounds__(256) void rank_hist_kernel(const int* __restrict__ dst,
                                                        int* __restrict__ cnt,
                                                        int* __restrict__ rank, int E) {
  int i = blockIdx.x * 256 + threadIdx.x;
  if (i >= E) return;
  rank[i] = atomicAdd(&cnt[dst[i]], 1);
}

// ---- 3-phase parallel exclusive scan of (cnt[i]+1), 512 elems per block ----
__global__ __launch_bounds__(256) void scan_part_kernel(const int* __restrict__ cnt,
                                                        int* __restrict__ bpart, int n) {
  __shared__ int red[256];
  int base = blockIdx.x * 512;
  int t = threadIdx.x;
  int s = 0;
  int i0 = base + t, i1 = base + 256 + t;
  if (i0 < n) s += cnt[i0] + 1;
  if (i1 < n) s += cnt[i1] + 1;
  red[t] = s;
  __syncthreads();
  for (int off = 128; off > 0; off >>= 1) {
    if (t < off) red[t] += red[t + off];
    __syncthreads();
  }
  if (t == 0) bpart[blockIdx.x] = red[0];
}

// scan of block partials + (fused) graph-boundary binary search
__global__ __launch_bounds__(1024) void scan_top_kernel(const int* __restrict__ bpart,
                                                        int* __restrict__ boff,
                                                        int* __restrict__ row_ptr,
                                                        const int* __restrict__ batch,
                                                        int* __restrict__ gstart,
                                                        int B, int n) {
  __shared__ int buf[1024];
  int t = threadIdx.x;
  buf[t] = (t < B) ? bpart[t] : 0;
  __syncthreads();
  for (int off = 1; off < 1024; off <<= 1) {
    int v = (t >= off) ? buf[t - off] : 0;
    __syncthreads();
    buf[t] += v;
    __syncthreads();
  }
  if (t < B) boff[t] = (t == 0) ? 0 : buf[t - 1];
  if (t == 0) row_ptr[n] = buf[1023];
  // fused gbound: graph g's node range start (batch is sorted)
  if (t <= GNUM) {
    int lo = 0, hi = n;
    while (lo < hi) {
      int mid = (lo + hi) >> 1;
      if (batch[mid] < t) lo = mid + 1; else hi = mid;
    }
    gstart[t] = lo;
  }
}

// writes row_ptr (exclusive prefix of cnt[i]+1)
__global__ __launch_bounds__(256) void scan_write_kernel(const int* __restrict__ cnt,
                                                         const int* __restrict__ boff,
                                                         int* __restrict__ row_ptr, int n) {
  __shared__ int red[256];
  int base = blockIdx.x * 512;
  int t = threadIdx.x;
  int i0 = base + 2 * t, i1 = base + 2 * t + 1;
  int v0 = (i0 < n) ? cnt[i0] + 1 : 0;
  int v1 = (i1 < n) ? cnt[i1] + 1 : 0;
  int val = v0 + v1;
  red[t] = val;
  __syncthreads();
  for (int off = 1; off < 256; off <<= 1) {
    int u = (t >= off) ? red[t - off] : 0;
    __syncthreads();
    red[t] += u;
    __syncthreads();
  }
  int o = boff[blockIdx.x] + red[t] - val;   // exclusive prefix for this pair
  if (i0 < n) row_ptr[i0] = o;
  if (i1 < n) row_ptr[i1] = o + v0;
}

// R19: XCD-sharded dst-windowed placement. block bid: chunk = bid>>3,
// window j = bid&7 (dst in [j*W, j*W+W)). Round-robin dispatch pins window
// j's output lines to XCD j's L2 -> each line finalized in cache, one
// writeback. Only dst is read before the window check.
__global__ __launch_bounds__(256) void place_x_kernel(const int* __restrict__ src,
                                                      const int* __restrict__ dst,
                                                      const int* __restrict__ rank,
                                                      const int* __restrict__ row_ptr,
                                                      const float* __restrict__ ea,
                                                      int* __restrict__ csr_src,
                                                      _Float16* __restrict__ ea_csr,
                                                      int E, int W) {
  int j = blockIdx.x & 7;
  int i = (blockIdx.x >> 3) * 256 + threadIdx.x;
  if (i >= E) return;
  int d = dst[i];
  if ((unsigned)(d - j * W) >= (unsigned)W) return;   // not this block's window
  int p = row_ptr[d] + rank[i];
  csr_src[p] = src[i];
  float4 e0 = *(const float4*)&ea[(size_t)i * 8];
  float4 e1 = *(const float4*)&ea[(size_t)i * 8 + 4];
  h8 v;
  v[0] = (_Float16)e0.x; v[1] = (_Float16)e0.y; v[2] = (_Float16)e0.z; v[3] = (_Float16)e0.w;
  v[4] = (_Float16)e1.x; v[5] = (_Float16)e1.y; v[6] = (_Float16)e1.z; v[7] = (_Float16)e1.w;
  *(h8*)&ea_csr[(size_t)p * 8] = v;
}

// fill self-loop slot (last of each segment) with segment-mean attrs.
// 8 threads per node (one per edge channel).
__global__ __launch_bounds__(256) void selfloop_kernel(const int* __restrict__ row_ptr,
                                                       int* __restrict__ csr_src,
                                                       _Float16* __restrict__ ea_csr, int n) {
  int idx = blockIdx.x * 256 + threadIdx.x;
  int i = idx >> 3, c = idx & 7;
  if (i >= n) return;
  int s = row_ptr[i], e = row_ptr[i + 1] - 1;   // [s,e) real edges, e = self slot
  float a = 0.f;
  for (int j = s; j < e; j++) a += (float)ea_csr[(size_t)j * 8 + c];
  float inv = 1.f / fmaxf((float)(e - s), 1.f);
  ea_csr[(size_t)e * 8 + c] = (_Float16)(a * inv);
  if (c == 0) csr_src[e] = i;
}

// pack all 6 weight matrices f32 -> fp16 MFMA B-fragment order in one launch.
// blockIdx.y selects matrix; zero-pad K to Kpad.
__global__ __launch_bounds__(256) void pack_all_kernel(
    const float* __restrict__ wl1, _Float16* __restrict__ p1l,
    const float* __restrict__ wr1, _Float16* __restrict__ p1r,
    const float* __restrict__ wl2, _Float16* __restrict__ p2l,
    const float* __restrict__ wr2, _Float16* __restrict__ p2r,
    const float* __restrict__ wl3, _Float16* __restrict__ p3l,
    const float* __restrict__ wr3, _Float16* __restrict__ p3r) {
  int y = blockIdx.y;
  const float* w; _Float16* wp; int Kreal, Kpad, NC;
  switch (y) {
    case 0: w = wl1; wp = p1l; Kreal = 16;  Kpad = 32;  NC = 128; break;
    case 1: w = wr1; wp = p1r; Kreal = 16;  Kpad = 32;  NC = 128; break;
    case 2: w = wl2; wp = p2l; Kreal = 128; Kpad = 128; NC = 128; break;
    case 3: w = wr2; wp = p2r; Kreal = 128; Kpad = 128; NC = 128; break;
    case 4: w = wl3; wp = p3l; Kreal = 128; Kpad = 128; NC = 32;  break;
    default: w = wr3; wp = p3r; Kreal = 128; Kpad = 128; NC = 32; break;
  }
  int KB = Kpad / 32;
  int total = (NC / 16) * KB * 64;
  int idx = blockIdx.x * 256 + threadIdx.x;
  if (idx >= total) return;
  int lane = idx & 63;
  int blk = idx >> 6;
  int nt = blk / KB, kb = blk % KB;
  int col = nt * 16 + (lane & 15);
  int krow = kb * 32 + (lane >> 4) * 8;
  h8 v;
#pragma unroll
  for (int j = 0; j < 8; j++)
    v[j] = (krow + j < Kreal) ? (_Float16)w[(size_t)(krow + j) * NC + col] : (_Float16)0.f;
  *(h8*)&wp[(size_t)idx * 8] = v;
}

// ---------------------------------------------------------------- node transform GEMMs

// fp16 MFMA, K=128. 256 thr = 4 waves, 16 nodes/wave, 64 nodes/block.
// (unfused: gridDim.y selects L/R; A re-read is L3-cheap — R16 fusion lost.)
template <int K, int NCOLS>
__global__ __launch_bounds__(256) void k1m_kernel(const _Float16* __restrict__ x,
                                                  const _Float16* __restrict__ wp0,
                                                  const float* __restrict__ b0,
                                                  _Float16* __restrict__ out0,
                                                  const _Float16* __restrict__ wp1,
                                                  const float* __restrict__ b1,
                                                  _Float16* __restrict__ out1, int n) {
  constexpr int NT = NCOLS / 16, KB = K / 32;
  const _Float16* wp = blockIdx.y ? wp1 : wp0;
  const float* b = blockIdx.y ? b1 : b0;
  _Float16* out = blockIdx.y ? out1 : out0;

  int tid = threadIdx.x;
  int wave = tid >> 6, lane = tid & 63;
  int m = lane & 15, quad = lane >> 4;
  int node0 = blockIdx.x * 64 + wave * 16;

  h8 afrag[KB];
  int anode = node0 + m;
  if (anode < n) {
#pragma unroll
    for (int kb = 0; kb < KB; kb++)
      afrag[kb] = *(const h8*)&x[(size_t)anode * K + kb * 32 + quad * 8];
  } else {
#pragma unroll
    for (int kb = 0; kb < KB; kb++) afrag[kb] = (h8)(_Float16)0.f;
  }

  f4 acc[NT] = {};
#pragma unroll
  for (int nt = 0; nt < NT; nt++) {
#pragma unroll
    for (int kb = 0; kb < KB; kb++) {
      h8 bfrag = *(const h8*)&wp[((size_t)(nt * KB + kb) * 64 + lane) * 8];
      acc[nt] = __builtin_amdgcn_mfma_f32_16x16x32_f16(afrag[kb], bfrag, acc[nt], 0, 0, 0);
    }
  }

#pragma unroll
  for (int nt = 0; nt < NT; nt++) {
#pragma unroll
    for (int r = 0; r < 4; r++) {
      int row = node0 + quad * 4 + r;
      if (row < n) {
        int col = nt * 16 + m;
        out[(size_t)row * NCOLS + col] = (_Float16)(acc[nt][r] + b[col]);
      }
    }
  }
}

// fp16 MFMA, Kreal=16 zero-padded to 32 (layer 1); reads f32 x directly and
// converts in-register.
template <int NCOLS>
__global__ __launch_bounds__(256) void k1m16_kernel(const float* __restrict__ x,
                                                    const _Float16* __restrict__ wp0,
                                                    const float* __restrict__ b0,
                                                    _Float16* __restrict__ out0,
                                                    const _Float16* __restrict__ wp1,
                                                    const float* __restrict__ b1,
                                                    _Float16* __restrict__ out1, int n) {
  constexpr int NT = NCOLS / 16;
  const _Float16* wp = blockIdx.y ? wp1 : wp0;
  const float* b = blockIdx.y ? b1 : b0;
  _Float16* out = blockIdx.y ? out1 : out0;

  int tid = threadIdx.x;
  int wave = tid >> 6, lane = tid & 63;
  int m = lane & 15, quad = lane >> 4;
  int node0 = blockIdx.x * 64 + wave * 16;

  int anode = node0 + m;
  h8 afrag = (h8)(_Float16)0.f;
  if (anode < n && quad < 2) {
    float4 v0 = *(const float4*)&x[(size_t)anode * 16 + quad * 8];
    float4 v1 = *(const float4*)&x[(size_t)anode * 16 + quad * 8 + 4];
    afrag[0] = (_Float16)v0.x; afrag[1] = (_Float16)v0.y;
    afrag[2] = (_Float16)v0.z; afrag[3] = (_Float16)v0.w;
    afrag[4] = (_Float16)v1.x; afrag[5] = (_Float16)v1.y;
    afrag[6] = (_Float16)v1.z; afrag[7] = (_Float16)v1.w;
  }

  f4 acc[NT] = {};
#pragma unroll
  for (int nt = 0; nt < NT; nt++) {
    h8 bfrag = *(const h8*)&wp[((size_t)nt * 64 + lane) * 8];
    acc[nt] = __builtin_amdgcn_mfma_f32_16x16x32_f16(afrag, bfrag, acc[nt], 0, 0, 0);
  }

#pragma unroll
  for (int nt = 0; nt < NT; nt++) {
#pragma unroll
    for (int r = 0; r < 4; r++) {
      int row = node0 + quad * 4 + r;
      if (row < n) {
        int col = nt * 16 + m;
        out[(size_t)row * NCOLS + col] = (_Float16)(acc[nt][r] + b[col]);
      }
    }
  }
}

// ---------------------------------------------------------------- fused GATv2 edge+softmax+aggregate
// R15 champion (H=4): one node per wave, 64 lanes x 2 channels. Edge
// metadata on the scalar pipe. 3-stage software pipeline per iteration:
//   A: idx+ea s_loads for pair p+2   (breaks s_load->gather serialization)
//   B: xl gathers for pair p+1       (indices resident since last iter)
//   C: compute pair p                (DPP reduce, fdot2, masked tail)
// One-pass softmax (no max-shift; logits O(1)); att pre-scaled by log2(e).
__global__ __launch_bounds__(256) void k2w_kernel(
    const _Float16* __restrict__ xl, const _Float16* __restrict__ xr,
    const int* __restrict__ row_ptr, const int* __restrict__ csr_src,
    const _Float16* __restrict__ ea_csr, const float* __restrict__ we,
    const float* __restrict__ att, const float* __restrict__ bc,
    _Float16* __restrict__ out, int n) {
  int tid = threadIdx.x;
  int lane = tid & 63;
  int node = blockIdx.x * 4 + (tid >> 6);
  if (node >= n) return;
  int c0 = lane << 1;          // 2 channels per lane; head = lane>>4

  int start = __builtin_amdgcn_readfirstlane(row_ptr[node]);
  int end   = __builtin_amdgcn_readfirstlane(row_ptr[node + 1]);   // len >= 1 (self loop)
  int len = end - start;
  int pairs = (len + 1) >> 1;

  // ---- pipeline prologue: pair0 idx+ea first (longest latency) ----
  int j1 = (start + 1 < end) ? start + 1 : start;
  float m1 = (start + 1 < end) ? 1.f : 0.f;
  int s0 = __builtin_amdgcn_readfirstlane(csr_src[start]);
  int s1 = __builtin_amdgcn_readfirstlane(csr_src[j1]);
  h8 e0 = *(const h8*)&ea_csr[(size_t)start * 8];
  h8 e1 = *(const h8*)&ea_csr[(size_t)j1 * 8];

  // per-lane tables (independent work to overlap the s_loads above)
  h2 w2[8];
#pragma unroll
  for (int k = 0; k < 8; k++) {
    float2 v = *(const float2*)&we[k * 128 + c0];
    w2[k] = h2{(_Float16)v.x, (_Float16)v.y};
  }
  const float LOG2E = 1.44269504088896f;
  float2 av = *(const float2*)&att[c0];
  h2 a2 = h2{(_Float16)(av.x * LOG2E), (_Float16)(av.y * LOG2E)};
  h2 xr2 = *(const h2*)&xr[(size_t)node * 128 + c0];
  const h2 p2 = h2{(_Float16)0.2f, (_Float16)0.2f};

  // pair0 gathers
  h2 x0 = *(const h2*)&xl[(uint32_t)s0 * 128u + (uint32_t)c0];
  h2 x1 = *(const h2*)&xl[(uint32_t)s1 * 128u + (uint32_t)c0];

  // pair1 idx+ea
  int jn = start + 2;
  int k0 = (jn < end) ? jn : start;
  int k1 = (jn + 1 < end) ? jn + 1 : k0;
  float m1n = (jn + 1 < end) ? 1.f : 0.f;
  int s0n = __builtin_amdgcn_readfirstlane(csr_src[k0]);
  int s1n = __builtin_amdgcn_readfirstlane(csr_src[k1]);
  h8 e0n = *(const h8*)&ea_csr[(size_t)k0 * 8];
  h8 e1n = *(const h8*)&ea_csr[(size_t)k1 * 8];

  float s = 0.f, acc0 = 0.f, acc1 = 0.f;

#pragma unroll 2
  for (int p = 0; p < pairs; p++) {
    // ---- stage A: idx+ea for pair p+2 (scalar pipe, SALU clamps) ----
    int ja = start + 2 * (p + 2);
    int ka0 = (ja < end) ? ja : start;
    int ka1 = (ja + 1 < end) ? ja + 1 : ka0;
    float m1a = (ja + 1 < end) ? 1.f : 0.f;
    int s0a = __builtin_amdgcn_readfirstlane(csr_src[ka0]);
    int s1a = __builtin_amdgcn_readfirstlane(csr_src[ka1]);
    h8 e0a = *(const h8*)&ea_csr[(size_t)ka0 * 8];
    h8 e1a = *(const h8*)&ea_csr[(size_t)ka1 * 8];

    // ---- stage B: xl gathers for pair p+1 (indices already resident) ----
    h2 x0n = *(const h2*)&xl[(uint32_t)s0n * 128u + (uint32_t)c0];
    h2 x1n = *(const h2*)&xl[(uint32_t)s1n * 128u + (uint32_t)c0];

    // ---- stage C: compute pair p ----
    h2 t0 = x0 + xr2;
    h2 t1 = x1 + xr2;
#pragma unroll
    for (int k = 0; k < 8; k++) {
      t0 += h2{e0[k], e0[k]} * w2[k];
      t1 += h2{e1[k], e1[k]} * w2[k];
    }
    t0 = __builtin_elementwise_max(t0, t0 * p2);
    t1 = __builtin_elementwise_max(t1, t1 * p2);
    float part0 = hdot2(t0, a2, 0.f);
    float part1 = hdot2(t1, a2, 0.f);
    // 16-lane head reduce, pure VALU (DPP)
    part0 = dppadd<0xB1>(part0);   part1 = dppadd<0xB1>(part1);
    part0 = dppadd<0x4E>(part0);   part1 = dppadd<0x4E>(part1);
    part0 = dppadd<0x141>(part0);  part1 = dppadd<0x141>(part1);
    part0 = dppadd<0x140>(part0);  part1 = dppadd<0x140>(part1);
    float pe0 = __builtin_amdgcn_exp2f(part0);
    float pe1 = __builtin_amdgcn_exp2f(part1) * m1;   // mask dummy edge
    s += pe0 + pe1;
    acc0 += pe0 * (float)x0[0] + pe1 * (float)x1[0];
    acc1 += pe0 * (float)x0[1] + pe1 * (float)x1[1];

    // ---- rotate pipeline registers (renamed under unroll) ----
    x0 = x0n; x1 = x1n; e0 = e0n; e1 = e1n; m1 = m1n;
    s0n = s0a; s1n = s1a; e0n = e0a; e1n = e1a; m1n = m1a;
  }

  float inv = 1.f / (s + 1e-16f);
  float2 bv = *(const float2*)&bc[c0];
  float v0 = acc0 * inv + bv.x;
  float v1 = acc1 * inv + bv.y;
  v0 = v0 > 0.f ? v0 : (__expf(v0) - 1.f);   // elu
  v1 = v1 > 0.f ? v1 : (__expf(v1) - 1.f);
  *(h2*)&out[(size_t)node * 128 + c0] = h2{(_Float16)v0, (_Float16)v1};
}

// H=1 path (layer 3): R7 2-wide pipeline, 8 lanes/node + DPP/fdot2.
template <int H>
__global__ __launch_bounds__(128) void k2_kernel(
    const _Float16* __restrict__ xl, const _Float16* __restrict__ xr,
    const int* __restrict__ row_ptr, const int* __restrict__ csr_src,
    const _Float16* __restrict__ ea_csr, const float* __restrict__ we,
    const float* __restrict__ att, const float* __restrict__ bc,
    _Float16* __restrict__ out, int n) {
  constexpr int HC = H * 32;
  constexpr int NL = HC / 4;   // lanes per node (8)
  constexpr int NPB = 128 / NL;

  int tid = threadIdx.x;
  int ln = tid / NL, q = tid % NL;
  int c0 = 4 * q;
  int node = blockIdx.x * NPB + ln;
  if (node >= n) return;

  h2 w2[8][2];
#pragma unroll
  for (int k = 0; k < 8; k++) {
    float4 v = *(const float4*)&we[k * HC + c0];
    w2[k][0] = h2{(_Float16)v.x, (_Float16)v.y};
    w2[k][1] = h2{(_Float16)v.z, (_Float16)v.w};
  }
  const float LOG2E = 1.44269504088896f;
  float4 av = *(const float4*)&att[c0];
  h2 a0 = h2{(_Float16)(av.x * LOG2E), (_Float16)(av.y * LOG2E)};
  h2 a1 = h2{(_Float16)(av.z * LOG2E), (_Float16)(av.w * LOG2E)};
  h4 xrh = *(const h4*)&xr[(size_t)node * HC + c0];
  h2 xr0 = h2{xrh[0], xrh[1]}, xr1 = h2{xrh[2], xrh[3]};
  const h2 p2 = h2{(_Float16)0.2f, (_Float16)0.2f};

  float acc[4] = {0.f, 0.f, 0.f, 0.f};
  float s = 0.f;

  int start = row_ptr[node], end = row_ptr[node + 1];   // len >= 1 (self loop)
  int len = end - start;
  int pairs = (len + 1) >> 1;

  // prologue: load pair 0 (clamped)
  int j1 = (start + 1 < end) ? start + 1 : start;
  float m1 = (start + 1 < end) ? 1.f : 0.f;
  int s0 = csr_src[start], s1 = csr_src[j1];
  h8 e0 = *(const h8*)&ea_csr[(size_t)start * 8];
  h8 e1 = *(const h8*)&ea_csr[(size_t)j1 * 8];
  h4 x0 = *(const h4*)&xl[(size_t)s0 * HC + c0];
  h4 x1 = *(const h4*)&xl[(size_t)s1 * HC + c0];

#pragma unroll 2
  for (int p = 0; p < pairs; p++) {
    // ---- issue next pair's src/ea loads (clamped; unused garbage on last) ----
    int jn = start + 2 * (p + 1);
    int k0 = (jn < end) ? jn : start;
    int k1 = (jn + 1 < end) ? jn + 1 : k0;
    float nm1 = (jn + 1 < end) ? 1.f : 0.f;
    int ns0 = csr_src[k0], ns1 = csr_src[k1];
    h8 ne0 = *(const h8*)&ea_csr[(size_t)k0 * 8];
    h8 ne1 = *(const h8*)&ea_csr[(size_t)k1 * 8];

    // ---- logits for current pair (two independent chains) ----
    h2 t00 = h2{x0[0], x0[1]} + xr0;
    h2 t01 = h2{x0[2], x0[3]} + xr1;
    h2 t10 = h2{x1[0], x1[1]} + xr0;
    h2 t11 = h2{x1[2], x1[3]} + xr1;
#pragma unroll
    for (int k = 0; k < 8; k++) {
      h2 ev0 = h2{e0[k], e0[k]};
      h2 ev1 = h2{e1[k], e1[k]};
      t00 += ev0 * w2[k][0];
      t01 += ev0 * w2[k][1];
      t10 += ev1 * w2[k][0];
      t11 += ev1 * w2[k][1];
    }
    t00 = __builtin_elementwise_max(t00, t00 * p2);
    t01 = __builtin_elementwise_max(t01, t01 * p2);
    t10 = __builtin_elementwise_max(t10, t10 * p2);
    t11 = __builtin_elementwise_max(t11, t11 * p2);
    float part0 = hdot2(t00, a0, hdot2(t01, a1, 0.f));
    float part1 = hdot2(t10, a0, hdot2(t11, a1, 0.f));

    // ---- issue next pair's xl gathers before the reduce chain ----
    h4 nx0 = *(const h4*)&xl[(size_t)ns0 * HC + c0];
    h4 nx1 = *(const h4*)&xl[(size_t)ns1 * HC + c0];

    // ---- 8-lane reduce (DPP, pure VALU), exp, accumulate ----
    part0 = dppadd<0xB1>(part0);   part1 = dppadd<0xB1>(part1);
    part0 = dppadd<0x4E>(part0);   part1 = dppadd<0x4E>(part1);
    part0 = dppadd<0x141>(part0);  part1 = dppadd<0x141>(part1);
    float pe0 = __builtin_amdgcn_exp2f(part0);
    float pe1 = __builtin_amdgcn_exp2f(part1) * m1;
    s += pe0 + pe1;
#pragma unroll
    for (int i = 0; i < 4; i++)
      acc[i] += pe0 * (float)x0[i] + pe1 * (float)x1[i];

    // ---- rotate pipeline registers (renamed away under unroll) ----
    s0 = ns0; s1 = ns1; e0 = ne0; e1 = ne1; x0 = nx0; x1 = nx1; m1 = nm1;
  }

  float inv = 1.f / (s + 1e-16f);
  h4 o;
#pragma unroll
  for (int i = 0; i < 4; i++) {
    float v = acc[i] * inv + bc[c0 + i];
    o[i] = (_Float16)(v > 0.f ? v : (__expf(v) - 1.f));   // elu
  }
  *(h4*)&out[(size_t)node * HC + c0] = o;
}

// ---------------------------------------------------------------- fused pooling + MLP
// block g: mean over graph g's node range -> fc1 (elu) -> fc2 -> out. gmean
// stays in LDS. h2-vectorized accumulation (16 rowgroups x 16 ch-pairs).
__global__ __launch_bounds__(256) void poolfc_kernel(const _Float16* __restrict__ h,
                                                     const int* __restrict__ gstart,
                                                     const float* __restrict__ w1,
                                                     const float* __restrict__ b1,
                                                     const float* __restrict__ w2,
                                                     const float* __restrict__ b2,
                                                     float* __restrict__ out) {
  __shared__ float redx[256];
  __shared__ float redy[256];
  __shared__ float g[32];
  __shared__ float a1[64];
  int gi = blockIdx.x;
  int t = threadIdx.x;
  int s = gstart[gi], e = gstart[gi + 1];
  int cp = t & 15, rg = t >> 4;   // t = rg*16 + cp
  float ax = 0.f, ay = 0.f;
  for (int i = s + rg; i < e; i += 16) {
    h2 v = *(const h2*)&h[(size_t)i * 32 + cp * 2];
    ax += (float)v[0]; ay += (float)v[1];
  }
  redx[t] = ax; redy[t] = ay;
  __syncthreads();
  if (t < 128) { redx[t] += redx[t + 128]; redy[t] += redy[t + 128]; }
  __syncthreads();
  if (t < 64) { redx[t] += redx[t + 64]; redy[t] += redy[t + 64]; }
  __syncthreads();
  if (t < 32) { redx[t] += redx[t + 32]; redy[t] += redy[t + 32]; }
  __syncthreads();
  if (t < 16) {
    float inv = 1.f / fmaxf((float)(e - s), 1.f);
    g[2 * t]     = (redx[t] + redx[t + 16]) * inv;
    g[2 * t + 1] = (redy[t] + redy[t + 16]) * inv;
  }
  __syncthreads();
  if (t < 64) {
    float v = b1[t];
    for (int k = 0; k < 32; k++) v += g[k] * w1[k * 64 + t];
    a1[t] = v > 0.f ? v : (__expf(v) - 1.f);
  }
  __syncthreads();
  if (t < 4) {
    float o = b2[t];
    for (int k = 0; k < 64; k++) o += a1[k] * w2[k * 4 + t];
    out[gi * 4 + t] = o;
  }
}

// ---------------------------------------------------------------- launch

extern "C" void kernel_launch(void* const* d_in, const int* in_sizes, int n_in,
                              void* d_out, int out_size, void* d_ws, size_t ws_size,
                              hipStream_t stream) {
  const float* x     = (const float*)d_in[0];
  const int*   ei    = (const int*)d_in[1];
  const float* eattr = (const float*)d_in[2];
  const int*   batch = (const int*)d_in[3];
  const float *wl1 = (const float*)d_in[4],  *bl1 = (const float*)d_in[5];
  const float *wr1 = (const float*)d_in[6],  *br1 = (const float*)d_in[7];
  const float *we1 = (const float*)d_in[8],  *at1 = (const float*)d_in[9];
  const float *bc1 = (const float*)d_in[10];
  const float *wl2 = (const float*)d_in[11], *bl2 = (const float*)d_in[12];
  const float *wr2 = (const float*)d_in[13], *br2 = (const float*)d_in[14];
  const float *we2 = (const float*)d_in[15], *at2 = (const float*)d_in[16];
  const float *bc2 = (const float*)d_in[17];
  const float *wl3 = (const float*)d_in[18], *bl3 = (const float*)d_in[19];
  const float *wr3 = (const float*)d_in[20], *br3 = (const float*)d_in[21];
  const float *we3 = (const float*)d_in[22], *at3 = (const float*)d_in[23];
  const float *bc3 = (const float*)d_in[24];
  const float *wf1 = (const float*)d_in[25], *bf1 = (const float*)d_in[26];
  const float *wf2 = (const float*)d_in[27], *bf2 = (const float*)d_in[28];

  int N = in_sizes[0] / 16;
  int E = in_sizes[1] / 2;
  const int* srcp = ei;
  const int* dstp = ei + E;
  int EA = E + N;             // CSR entries incl. self-loops
  int NB = (N + 511) / 512;   // scan blocks (<=1024)
  int W = (N + 7) / 8;        // dst-window width for sharded place

  char* wsb = (char*)d_ws;
  size_t off = 0;
  auto alloc = [&](size_t bytes) -> char* {
    char* p = wsb + off;
    off += (bytes + 255) & ~(size_t)255;
    return p;
  };
  int*       cnt     = (int*)alloc((size_t)N * 4);
  int*       row_ptr = (int*)alloc((size_t)(N + 1) * 4);
  int*       rank    = (int*)alloc((size_t)E * 4);
  int*       bpart   = (int*)alloc((size_t)1024 * 4);
  int*       boff    = (int*)alloc((size_t)1024 * 4);
  int*       csr_src = (int*)alloc((size_t)EA * 4);
  _Float16*  ea_csr  = (_Float16*)alloc((size_t)EA * 8 * 2);
  _Float16*  xl      = (_Float16*)alloc((size_t)N * 128 * 2);
  _Float16*  xr      = (_Float16*)alloc((size_t)N * 128 * 2);
  _Float16*  h16     = (_Float16*)alloc((size_t)N * 128 * 2);
  _Float16*  h3      = (_Float16*)alloc((size_t)N * 32 * 2);
  int*       gstart  = (int*)alloc((size_t)(GNUM + 1) * 4);
  _Float16*  wp1l    = (_Float16*)alloc((size_t)32 * 128 * 2);
  _Float16*  wp1r    = (_Float16*)alloc((size_t)32 * 128 * 2);
  _Float16*  wp2l    = (_Float16*)alloc((size_t)128 * 128 * 2);
  _Float16*  wp2r    = (_Float16*)alloc((size_t)128 * 128 * 2);
  _Float16*  wp3l    = (_Float16*)alloc((size_t)128 * 32 * 2);
  _Float16*  wp3r    = (_Float16*)alloc((size_t)128 * 32 * 2);

  hipMemsetAsync(cnt, 0, (size_t)N * 4, stream);

  rank_hist_kernel<<<(E + 255) / 256, 256, 0, stream>>>(dstp, cnt, rank, E);
  scan_part_kernel<<<NB, 256, 0, stream>>>(cnt, bpart, N);
  scan_top_kernel<<<1, 1024, 0, stream>>>(bpart, boff, row_ptr, batch, gstart, NB, N);
  scan_write_kernel<<<NB, 256, 0, stream>>>(cnt, boff, row_ptr, N);
  place_x_kernel<<<((E + 255) / 256) * 8, 256, 0, stream>>>(
      srcp, dstp, rank, row_ptr, eattr, csr_src, ea_csr, E, W);
  selfloop_kernel<<<(N * 8 + 255) / 256, 256, 0, stream>>>(row_ptr, csr_src, ea_csr, N);
  pack_all_kernel<<<dim3(8, 6), 256, 0, stream>>>(wl1, wp1l, wr1, wp1r,
                                                  wl2, wp2l, wr2, wp2r,
                                                  wl3, wp3l, wr3, wp3r);

  // layer 1: K=16 -> 128 (fp16 MFMA, K zero-padded to 32, f32 input)
  k1m16_kernel<128><<<dim3((N + 63) / 64, 2), 256, 0, stream>>>(
      x, wp1l, bl1, xl, wp1r, br1, xr, N);
  k2w_kernel<<<(N + 3) / 4, 256, 0, stream>>>(xl, xr, row_ptr, csr_src, ea_csr,
                                              we1, at1, bc1, h16, N);
  // layer 2: K=128 -> 128 (fp16 MFMA)
  k1m_kernel<128, 128><<<dim3((N + 63) / 64, 2), 256, 0, stream>>>(
      h16, wp2l, bl2, xl, wp2r, br2, xr, N);
  k2w_kernel<<<(N + 3) / 4, 256, 0, stream>>>(xl, xr, row_ptr, csr_src, ea_csr,
                                              we2, at2, bc2, h16, N);
  // layer 3: K=128 -> 32 (fp16 MFMA, single head)
  k1m_kernel<128, 32><<<dim3((N + 63) / 64, 2), 256, 0, stream>>>(
      h16, wp3l, bl3, xl, wp3r, br3, xr, N);
  k2_kernel<1><<<(N + 15) / 16, 128, 0, stream>>>(xl, xr, row_ptr, csr_src, ea_csr,
                                                  we3, at3, bc3, h3, N);

  poolfc_kernel<<<GNUM, 256, 0, stream>>>(h3, gstart, wf1, bf1, wf2, bf2, (float*)d_out);
}